// Round 10
// baseline (150.323 us; speedup 1.0000x reference)
//
#include <hip/hip_runtime.h>

// LinearAttentionCell: chunked linear attention, bf16 MFMA.
// R10: wave-private staging — each wave stages its own operand rows into
// private LDS (dup reads hit L2), eliminating ALL K-loop barriers; waves
// free-run on private counted vmcnt. proj/kvp epilogues = R8 form.

constexpr int Bn  = 8;
constexpr int Sn  = 2048;
constexpr int Cn  = 512;
constexpr int Tn  = 128;
constexpr int NCn = 16;
constexpr float DKf = 0.04419417382415922f;     // 1/sqrt(512)

typedef __attribute__((ext_vector_type(8))) short bf16x8;
typedef __attribute__((ext_vector_type(4))) float f32x4;

__device__ __forceinline__ unsigned short f2bf(float f) {   // RNE
  unsigned u = __float_as_uint(f);
  u = (u + 0x7fffu + ((u >> 16) & 1u)) >> 16;
  return (unsigned short)u;
}
__device__ __forceinline__ float bf2f(unsigned short h) {
  return __uint_as_float(((unsigned)h) << 16);
}
__device__ __forceinline__ float phi_f(float u) {
  float s = u * DKf;
  return s > 0.0f ? s + 1.0f : __expf(s);       // elu(s)+1
}

// ---- wave-private stage: 64 rows x 32 k (4 issues), swizzle ks^=(row>>1)&3 --
__device__ __forceinline__ void stage64x32w(const unsigned short* __restrict__ g,
                                            int ld, unsigned short* lds, int lane) {
#pragma unroll
  for (int i = 0; i < 4; ++i) {
    const int row = i * 16 + (lane >> 2);
    const int ks  = (lane & 3) ^ ((row >> 1) & 3);
    __builtin_amdgcn_global_load_lds(
        (const __attribute__((address_space(1))) void*)(g + (size_t)row * ld + ks * 8),
        (__attribute__((address_space(3))) void*)(lds + i * 512), 16, 0, 0);
  }
}

// ---- wave-private 64x64 GEMM over K: NO barriers, private dbuf + vmcnt(8) --
// wbase: this wave's 16 KB LDS (2 buffers x (A 2048 + B 2048) ushorts).
__device__ __forceinline__ void wmm_loop(const unsigned short* __restrict__ Ag, int lda,
                                         const unsigned short* __restrict__ Bg, int ldb,
                                         int nkt, unsigned short* wbase,
                                         f32x4 acc[4][4]) {
  const int lane = threadIdx.x & 63;
  const int fr = lane & 15, kb = lane >> 4;
  stage64x32w(Ag, lda, wbase, lane);
  stage64x32w(Bg, ldb, wbase + 2048, lane);
  int cur = 0;
  for (int kt = 0; kt < nkt; ++kt) {
    const int nxt = cur ^ 1;
    if (kt + 1 < nkt) {
      stage64x32w(Ag + (kt + 1) * 32, lda, wbase + nxt * 4096, lane);
      stage64x32w(Bg + (kt + 1) * 32, ldb, wbase + nxt * 4096 + 2048, lane);
      asm volatile("s_waitcnt vmcnt(8)" ::: "memory");   // tile kt landed
    } else {
      asm volatile("s_waitcnt vmcnt(0)" ::: "memory");
    }
    const unsigned short* Ac = wbase + cur * 4096;
    const unsigned short* Bc = Ac + 2048;
    bf16x8 af[4], bf[4];
#pragma unroll
    for (int m = 0; m < 4; ++m) {
      const int r = m * 16 + fr;
      af[m] = *(const bf16x8*)&Ac[r * 32 + ((kb ^ ((r >> 1) & 3)) << 3)];
    }
#pragma unroll
    for (int n = 0; n < 4; ++n) {
      const int r = n * 16 + fr;
      bf[n] = *(const bf16x8*)&Bc[r * 32 + ((kb ^ ((r >> 1) & 3)) << 3)];
    }
    __builtin_amdgcn_s_setprio(1);
#pragma unroll
    for (int m = 0; m < 4; ++m)
#pragma unroll
      for (int n = 0; n < 4; ++n)
        acc[m][n] = __builtin_amdgcn_mfma_f32_16x16x32_bf16(af[m], bf[n], acc[m][n], 0, 0, 0);
    __builtin_amdgcn_s_setprio(0);
    cur = nxt;
  }
}

// ---------------- casts ------------------------------------------------------
__global__ __launch_bounds__(256) void k_cast_x(const float* __restrict__ x,
                                                unsigned short* __restrict__ xb) {
  const size_t i8 = ((size_t)blockIdx.x * 256 + threadIdx.x) * 8;
  float4 a = *(const float4*)&x[i8];
  float4 b = *(const float4*)&x[i8 + 4];
  uint4 o;
  o.x = (unsigned)f2bf(a.x) | ((unsigned)f2bf(a.y) << 16);
  o.y = (unsigned)f2bf(a.z) | ((unsigned)f2bf(a.w) << 16);
  o.z = (unsigned)f2bf(b.x) | ((unsigned)f2bf(b.y) << 16);
  o.w = (unsigned)f2bf(b.z) | ((unsigned)f2bf(b.w) << 16);
  *(uint4*)&xb[i8] = o;
}

__global__ __launch_bounds__(256) void k_cast_w(const float* __restrict__ Wq,
                                                const float* __restrict__ Wk,
                                                const float* __restrict__ Wv,
                                                unsigned short* __restrict__ Wb) {
  const int z = blockIdx.y;
  const float* __restrict__ src = (z == 0) ? Wq : (z == 1 ? Wk : Wv);
  const size_t i8 = ((size_t)blockIdx.x * 256 + threadIdx.x) * 8;
  float4 a = *(const float4*)&src[i8];
  float4 b = *(const float4*)&src[i8 + 4];
  uint4 o;
  o.x = (unsigned)f2bf(a.x) | ((unsigned)f2bf(a.y) << 16);
  o.y = (unsigned)f2bf(a.z) | ((unsigned)f2bf(a.w) << 16);
  o.z = (unsigned)f2bf(b.x) | ((unsigned)f2bf(b.y) << 16);
  o.w = (unsigned)f2bf(b.z) | ((unsigned)f2bf(b.w) << 16);
  *(uint4*)&Wb[(size_t)z * Cn * Cn + i8] = o;
}

// ---------------- K1: projections (wave-private MFMA, XCD-local m-slabs) -----
__global__ __launch_bounds__(256) void k_proj(
    const unsigned short* __restrict__ xb, const unsigned short* __restrict__ Wb,
    unsigned short* __restrict__ PQ, unsigned short* __restrict__ PK,
    unsigned short* __restrict__ PKt, unsigned short* __restrict__ Vt,
    float* __restrict__ zsum)
{
  __shared__ unsigned short smem[4 * 8192];   // 64 KB: 4 waves x 2 buf x (A|B)
  __shared__ float zbuf[2][128];
  const int bid = blockIdx.x;
  const int xcd = bid & 7, idx = bid >> 3;            // idx in 0..191
  const int n = idx & 3, z = (idx >> 2) % 3, mloc = idx / 12;
  const int n0 = n * 128, m0 = (xcd * 16 + mloc) * 128;
  const int t = threadIdx.x, wid = t >> 6, lane = t & 63;
  const int wm = wid >> 1, wn = wid & 1;
  f32x4 acc[4][4];
  const f32x4 zero = {0.f, 0.f, 0.f, 0.f};
#pragma unroll
  for (int m = 0; m < 4; ++m)
#pragma unroll
    for (int nn = 0; nn < 4; ++nn) acc[m][nn] = zero;

  wmm_loop(xb + (size_t)(m0 + wm * 64) * Cn, Cn,
           Wb + (size_t)z * Cn * Cn + (size_t)(n0 + wn * 64) * Cn, Cn,
           Cn / 32, smem + wid * 8192, acc);

  float ps[4] = {0.f, 0.f, 0.f, 0.f};
#pragma unroll
  for (int m = 0; m < 4; ++m)
#pragma unroll
    for (int nn = 0; nn < 4; ++nn) {
      const int row0 = m0 + wm * 64 + m * 16 + ((lane >> 4) << 2);
      const int col  = n0 + wn * 64 + nn * 16 + (lane & 15);
      f32x4 v = acc[m][nn];
      if (z == 0) {
#pragma unroll
        for (int j = 0; j < 4; ++j)
          PQ[(size_t)(row0 + j) * Cn + col] = f2bf(phi_f(v[j]));
      } else if (z == 1) {
        ushort4 p;
#pragma unroll
        for (int j = 0; j < 4; ++j) {
          unsigned short u = f2bf(phi_f(v[j]));
          PK[(size_t)(row0 + j) * Cn + col] = u;
          (&p.x)[j] = u;
          ps[nn] += bf2f(u);
        }
        const int b = row0 >> 11, tq = row0 & (Sn - 1);
        *(ushort4*)&PKt[((size_t)b * Cn + col) * Sn + tq] = p;
      } else {
        ushort4 p;
#pragma unroll
        for (int j = 0; j < 4; ++j) (&p.x)[j] = f2bf(v[j]);
        const int b = row0 >> 11, tq = row0 & (Sn - 1);
        *(ushort4*)&Vt[((size_t)b * Cn + col) * Sn + tq] = p;
      }
    }

  if (z == 1) {   // block covers one (b, chunk) x cols n0..n0+127 completely
#pragma unroll
    for (int nn = 0; nn < 4; ++nn) {
      float v = ps[nn];
      v += __shfl_xor(v, 16); v += __shfl_xor(v, 32);   // reduce over kb
      if (lane < 16) zbuf[wm][wn * 64 + nn * 16 + lane] = v;
    }
    __syncthreads();
    if (t < 128) {
      const int b = m0 >> 11, ch = (m0 >> 7) & 15;
      zsum[((size_t)b * NCn + ch) * Cn + n0 + t] = zbuf[0][t] + zbuf[1][t];
    }
  }
}

// ---------------- K2a: A = tril(PQ_c PK_c^T) bf16; scale fully fused ---------
__global__ __launch_bounds__(256) void k_gram(
    const unsigned short* __restrict__ PQ, const unsigned short* __restrict__ PK,
    const float* __restrict__ zsum,
    unsigned short* __restrict__ Abuf, float* __restrict__ scale)
{
  __shared__ unsigned short smem[4 * 8192];
  __shared__ float rsmem[2][128];
  __shared__ float zpl[512];
  const int b = blockIdx.y, ch = blockIdx.x;
  const size_t base = ((size_t)b * Sn + ch * Tn) * Cn;
  const int t = threadIdx.x, wid = t >> 6, lane = t & 63;
  const int wm = wid >> 1, wn = wid & 1;
  f32x4 acc[4][4];
  const f32x4 zero = {0.f, 0.f, 0.f, 0.f};
#pragma unroll
  for (int m = 0; m < 4; ++m)
#pragma unroll
    for (int n = 0; n < 4; ++n) acc[m][n] = zero;

  wmm_loop(PQ + base + (size_t)(wm * 64) * Cn, Cn,
           PK + base + (size_t)(wn * 64) * Cn, Cn,
           Cn / 32, smem + wid * 8192, acc);

  float rsum[4][4];
#pragma unroll
  for (int m = 0; m < 4; ++m)
#pragma unroll
    for (int j = 0; j < 4; ++j) rsum[m][j] = 0.f;
#pragma unroll
  for (int m = 0; m < 4; ++m)
#pragma unroll
    for (int n = 0; n < 4; ++n) {
      f32x4 v = acc[m][n];
#pragma unroll
      for (int j = 0; j < 4; ++j) {
        const int row = wm * 64 + m * 16 + ((lane >> 4) << 2) + j;
        const int col = wn * 64 + n * 16 + (lane & 15);
        unsigned short u = (col <= row) ? f2bf(v[j]) : 0;
        Abuf[((size_t)(b * NCn + ch) * Tn + row) * Tn + col] = u;
        rsum[m][j] += bf2f(u);          // rowsum over the SAME rounded values
      }
    }
#pragma unroll
  for (int m = 0; m < 4; ++m)
#pragma unroll
    for (int j = 0; j < 4; ++j) {
      float r = rsum[m][j];
      r += __shfl_xor(r, 1); r += __shfl_xor(r, 2);
      r += __shfl_xor(r, 4); r += __shfl_xor(r, 8);
      if ((lane & 15) == 0)
        rsmem[wn][wm * 64 + m * 16 + ((lane >> 4) << 2) + j] = r;
    }
  // exclusive chunk-prefix of zsum -> zpl (LDS)
#pragma unroll
  for (int e = 0; e < 2; ++e) {
    const int c = t + e * 256;
    float s = 0.f;
    for (int ch2 = 0; ch2 < ch; ++ch2)
      s += zsum[((size_t)b * NCn + ch2) * Cn + c];
    zpl[c] = s;
  }
  __syncthreads();
  // per-row dot(PQ_row, zpl) + finalize scale (2 threads per row)
  const int row = t >> 1, half = (t & 1) * 256;
  const unsigned short* pq = PQ + base + (size_t)row * Cn + half;
  float dacc = 0.f;
  for (int i = 0; i < 256; i += 8) {
    uint4 q = *(const uint4*)(pq + i);
    dacc += bf2f((unsigned short)(q.x & 0xffff)) * zpl[half + i + 0]
          + bf2f((unsigned short)(q.x >> 16))    * zpl[half + i + 1]
          + bf2f((unsigned short)(q.y & 0xffff)) * zpl[half + i + 2]
          + bf2f((unsigned short)(q.y >> 16))    * zpl[half + i + 3]
          + bf2f((unsigned short)(q.z & 0xffff)) * zpl[half + i + 4]
          + bf2f((unsigned short)(q.z >> 16))    * zpl[half + i + 5]
          + bf2f((unsigned short)(q.w & 0xffff)) * zpl[half + i + 6]
          + bf2f((unsigned short)(q.w >> 16))    * zpl[half + i + 7];
  }
  dacc += __shfl_xor(dacc, 1);
  if ((t & 1) == 0)
    scale[(size_t)b * Sn + ch * Tn + row] =
        rsmem[0][row] + rsmem[1][row] + dacc + 1e-5f;
}

// ---- wave-private stage: 32 rows x 64 k (4 issues), swizzle ks ^= row&7 -----
__device__ __forceinline__ void stage32x64w(const unsigned short* __restrict__ g,
                                            int ld, unsigned short* lds, int lane) {
#pragma unroll
  for (int i = 0; i < 4; ++i) {
    const int row = i * 8 + (lane >> 3);
    const int ks  = (lane & 7) ^ (row & 7);
    __builtin_amdgcn_global_load_lds(
        (const __attribute__((address_space(1))) void*)(g + (size_t)row * ld + ks * 8),
        (__attribute__((address_space(3))) void*)(lds + i * 512), 16, 0, 0);
  }
}

// ---------------- K3a: fused KV + exclusive prefix (wave-private, BK=64) -----
// 512 blocks; XCD k owns batch k. Wave owns 32(c)x32(d) of the 64x64 M tile;
// walks 32 half-chunks with private dbuf + vmcnt(8); NO barriers at all.
// At each chunk boundary (kt even, ch>=1) the wave writes Mpre[ch] from acc.
__global__ __launch_bounds__(256) void k_kvp(
    const unsigned short* __restrict__ PKt, const unsigned short* __restrict__ Vt,
    unsigned short* __restrict__ Mpre)
{
  __shared__ unsigned short smem[4 * 8192];   // 64 KB: 4 waves x 2 buf x (A|B)
  const int bid = blockIdx.x;
  const int b = bid & 7, idx = bid >> 3;
  const int d0 = (idx & 7) * 64, c0 = (idx >> 3) * 64;
  const int t = threadIdx.x, wid = t >> 6, lane = t & 63;
  const int wm = wid >> 1, wn = wid & 1;
  const int fr = lane & 15, kb = lane >> 4;
  unsigned short* wbase = smem + wid * 8192;
  f32x4 acc[2][2];
  const f32x4 zero = {0.f, 0.f, 0.f, 0.f};
#pragma unroll
  for (int m = 0; m < 2; ++m)
#pragma unroll
    for (int n = 0; n < 2; ++n) acc[m][n] = zero;
  const unsigned short* Ag = PKt + ((size_t)b * Cn + c0 + wm * 32) * Sn;
  const unsigned short* Bg = Vt  + ((size_t)b * Cn + d0 + wn * 32) * Sn;
  stage32x64w(Ag, Sn, wbase, lane);
  stage32x64w(Bg, Sn, wbase + 2048, lane);
  int cur = 0;
  for (int kt = 0; kt < 32; ++kt) {           // half-chunks of 64 along t
    const int nxt = cur ^ 1;
    if ((kt & 1) == 0 && kt > 0) {            // chunk boundary: Mpre[ch] = acc
      const int ch = kt >> 1;
#pragma unroll
      for (int m = 0; m < 2; ++m)
#pragma unroll
        for (int n = 0; n < 2; ++n) {
          const int c_row = c0 + wm * 32 + m * 16 + (kb << 2);
          const int d     = d0 + wn * 32 + n * 16 + fr;
          ushort4 p;
#pragma unroll
          for (int j = 0; j < 4; ++j) (&p.x)[j] = f2bf(acc[m][n][j]);
          *(ushort4*)&Mpre[((size_t)(b * NCn + ch) * Cn + d) * Cn + c_row] = p;
        }
    }
    if (kt + 1 < 32) {
      stage32x64w(Ag + (kt + 1) * 64, Sn, wbase + nxt * 4096, lane);
      stage32x64w(Bg + (kt + 1) * 64, Sn, wbase + nxt * 4096 + 2048, lane);
      asm volatile("s_waitcnt vmcnt(8)" ::: "memory");   // drains tile kt + stores
    } else {
      asm volatile("s_waitcnt vmcnt(0)" ::: "memory");
    }
    const unsigned short* Ac = wbase + cur * 4096;
    const unsigned short* Bc = Ac + 2048;
    __builtin_amdgcn_s_setprio(1);
#pragma unroll
    for (int kk = 0; kk < 2; ++kk) {
      bf16x8 af[2], bf[2];
#pragma unroll
      for (int m = 0; m < 2; ++m) {
        const int r = m * 16 + fr;
        af[m] = *(const bf16x8*)&Ac[r * 64 + (((kk * 4 + kb) ^ (r & 7)) << 3)];
      }
#pragma unroll
      for (int n = 0; n < 2; ++n) {
        const int r = n * 16 + fr;
        bf[n] = *(const bf16x8*)&Bc[r * 64 + (((kk * 4 + kb) ^ (r & 7)) << 3)];
      }
#pragma unroll
      for (int m = 0; m < 2; ++m)
#pragma unroll
        for (int n = 0; n < 2; ++n)
          acc[m][n] = __builtin_amdgcn_mfma_f32_16x16x32_bf16(af[m], bf[n], acc[m][n], 0, 0, 0);
    }
    __builtin_amdgcn_s_setprio(0);
    cur = nxt;
  }
}

// ---------------- K3b: out = (A@V_c + PQ_c@Mpre_c) / scale (single write) ----
__global__ __launch_bounds__(256) void k_avinter(
    const unsigned short* __restrict__ Abuf, const unsigned short* __restrict__ Vt,
    const unsigned short* __restrict__ PQ, const unsigned short* __restrict__ Mpre,
    const float* __restrict__ scale, float* __restrict__ out)
{
  __shared__ unsigned short smem[4 * 8192];
  const int bid = blockIdx.x;
  const int logical = (bid & 7) * 64 + (bid >> 3);
  const int d0 = (logical & 3) * 128;
  const int ch = (logical >> 2) & 15;
  const int b  = logical >> 6;
  const int t0 = ch * Tn;
  const int t = threadIdx.x, wid = t >> 6, lane = t & 63;
  const int wm = wid >> 1, wn = wid & 1;
  unsigned short* wbase = smem + wid * 8192;
  f32x4 acc[4][4];
  const f32x4 zero = {0.f, 0.f, 0.f, 0.f};
#pragma unroll
  for (int m = 0; m < 4; ++m)
#pragma unroll
    for (int n = 0; n < 4; ++n) acc[m][n] = zero;

  // intra: A (128x128) @ V_c  (K = 128)
  wmm_loop(Abuf + (size_t)(b * NCn + ch) * Tn * Tn + (size_t)(wm * 64) * Tn, Tn,
           Vt + ((size_t)b * Cn + d0 + wn * 64) * Sn + t0, Sn,
           Tn / 32, wbase, acc);
  // inter: PQ_c @ Mpre_c  (K = 512)
  if (ch > 0)
    wmm_loop(PQ + ((size_t)b * Sn + t0 + wm * 64) * Cn, Cn,
             Mpre + ((size_t)(b * NCn + ch) * Cn + d0 + wn * 64) * Cn, Cn,
             Cn / 32, wbase, acc);

#pragma unroll
  for (int m = 0; m < 4; ++m)
#pragma unroll
    for (int n = 0; n < 4; ++n) {
      const int row0 = t0 + wm * 64 + m * 16 + ((lane >> 4) << 2);
      const int col  = d0 + wn * 64 + n * 16 + (lane & 15);
      f32x4 v = acc[m][n];
#pragma unroll
      for (int j = 0; j < 4; ++j) {
        const size_t sidx = (size_t)b * Sn + row0 + j;
        out[sidx * Cn + col] = v[j] / scale[sidx];
      }
    }
}

// ---------------- launch -----------------------------------------------------
extern "C" void kernel_launch(void* const* d_in, const int* in_sizes, int n_in,
                              void* d_out, int out_size, void* d_ws, size_t ws_size,
                              hipStream_t stream)
{
  const float* x  = (const float*)d_in[0];
  const float* Wq = (const float*)d_in[1];
  const float* Wk = (const float*)d_in[2];
  const float* Wv = (const float*)d_in[3];
  float* out = (float*)d_out;

  unsigned short* xb   = (unsigned short*)d_ws;
  unsigned short* Wb   = xb   + (size_t)Bn * Sn * Cn;          // 8.39M
  unsigned short* PQ   = Wb   + (size_t)3 * Cn * Cn;           // 0.79M
  unsigned short* PK   = PQ   + (size_t)Bn * Sn * Cn;
  unsigned short* PKt  = PK   + (size_t)Bn * Sn * Cn;
  unsigned short* Vt   = PKt  + (size_t)Bn * Sn * Cn;
  unsigned short* Abuf = Vt   + (size_t)Bn * Sn * Cn;          // 2.10M
  unsigned short* Mpre = Abuf + (size_t)Bn * NCn * Tn * Tn;    // 33.55M
  float* scale = (float*)(Mpre + (size_t)Bn * NCn * Cn * Cn);  // 16K
  float* zsum  = scale + (size_t)Bn * Sn;                      // 64K
  (void)ws_size; (void)in_sizes; (void)n_in; (void)out_size;

  hipLaunchKernelGGL(k_cast_x, dim3(4096), dim3(256), 0, stream, x, xb);
  hipLaunchKernelGGL(k_cast_w, dim3(128, 3), dim3(256), 0, stream, Wq, Wk, Wv, Wb);
  hipLaunchKernelGGL(k_proj, dim3(1536), dim3(256), 0, stream, xb, Wb, PQ, PK, PKt, Vt, zsum);
  hipLaunchKernelGGL(k_gram, dim3(NCn, Bn), dim3(256), 0, stream, PQ, PK, zsum, Abuf, scale);
  hipLaunchKernelGGL(k_kvp, dim3(512), dim3(256), 0, stream, PKt, Vt, Mpre);
  hipLaunchKernelGGL(k_avinter, dim3(512), dim3(256), 0, stream, Abuf, Vt, PQ, Mpre, scale, out);
}

// Round 12
// 125.083 us; speedup vs baseline: 1.2018x; 1.2018x over previous
//
#include <hip/hip_runtime.h>

// LinearAttentionCell: chunked linear attention, bf16 MFMA.
// R12 = R11 with stageB128 row/dst indexing fixed (was staging next-chunk
// rows into the wrong buffer half -> gram cols 64..127 corrupted).

constexpr int Bn  = 8;
constexpr int Sn  = 2048;
constexpr int Cn  = 512;
constexpr int Tn  = 128;
constexpr int NCn = 16;
constexpr float DKf = 0.04419417382415922f;     // 1/sqrt(512)

typedef __attribute__((ext_vector_type(8))) short bf16x8;
typedef __attribute__((ext_vector_type(4))) float f32x4;

__device__ __forceinline__ unsigned short f2bf(float f) {   // RNE
  unsigned u = __float_as_uint(f);
  u = (u + 0x7fffu + ((u >> 16) & 1u)) >> 16;
  return (unsigned short)u;
}
__device__ __forceinline__ float bf2f(unsigned short h) {
  return __uint_as_float(((unsigned)h) << 16);
}
__device__ __forceinline__ float phi_f(float u) {
  float s = u * DKf;
  return s > 0.0f ? s + 1.0f : __expf(s);       // elu(s)+1
}

// ---- stage a 128x32 bf16 tile global->LDS, swizzle kslot ^= (row>>1)&3 ------
__device__ __forceinline__ void stage128x32(const unsigned short* __restrict__ g,
                                            int ld, unsigned short* lds,
                                            int wid, int lane) {
#pragma unroll
  for (int cc = 0; cc < 2; ++cc) {
    const int row = cc * 64 + wid * 16 + (lane >> 2);
    const int ks  = (lane & 3) ^ ((row >> 1) & 3);
    const unsigned short* src = g + (size_t)row * ld + ks * 8;
    unsigned short* dst = lds + (size_t)(cc * 256 + wid * 64) * 8;  // wave-uniform
    __builtin_amdgcn_global_load_lds(
        (const __attribute__((address_space(1))) void*)src,
        (__attribute__((address_space(3))) void*)dst, 16, 0, 0);
  }
}

// ---- 128x128 out tile, 4 waves (2x2 of 64x64), 3-buffer dist-2 K loop -------
__device__ __forceinline__ void mm_loop(const unsigned short* __restrict__ Ag, int lda,
                                        const unsigned short* __restrict__ Bg, int ldb,
                                        int nkt,
                                        unsigned short* Al, unsigned short* Bl,
                                        f32x4 acc[4][4]) {
  const int t = threadIdx.x, wid = t >> 6, lane = t & 63;
  const int wm = wid >> 1, wn = wid & 1;
  const int fr = lane & 15, kb = lane >> 4;
  stage128x32(Ag, lda, Al, wid, lane);
  stage128x32(Bg, ldb, Bl, wid, lane);
  if (nkt > 1) {
    stage128x32(Ag + 32, lda, Al + 4096, wid, lane);
    stage128x32(Bg + 32, ldb, Bl + 4096, wid, lane);
  }
  int cur = 0;
  for (int kt = 0; kt < nkt; ++kt) {
    if (kt + 2 < nkt) {
      const int nx2 = (cur + 2 >= 3) ? cur - 1 : cur + 2;
      stage128x32(Ag + (kt + 2) * 32, lda, Al + nx2 * 4096, wid, lane);
      stage128x32(Bg + (kt + 2) * 32, ldb, Bl + nx2 * 4096, wid, lane);
      asm volatile("s_waitcnt vmcnt(8)" ::: "memory");
    } else if (kt + 1 < nkt) {
      asm volatile("s_waitcnt vmcnt(4)" ::: "memory");
    } else {
      asm volatile("s_waitcnt vmcnt(0)" ::: "memory");
    }
    __builtin_amdgcn_s_barrier();
    asm volatile("" ::: "memory");          // no ds_read hoist above barrier
    const unsigned short* Ac = Al + cur * 4096;
    const unsigned short* Bc = Bl + cur * 4096;
    bf16x8 af[4], bf[4];
#pragma unroll
    for (int m = 0; m < 4; ++m) {
      const int r = wm * 64 + m * 16 + fr;
      af[m] = *(const bf16x8*)&Ac[r * 32 + ((kb ^ ((r >> 1) & 3)) << 3)];
    }
#pragma unroll
    for (int n = 0; n < 4; ++n) {
      const int r = wn * 64 + n * 16 + fr;
      bf[n] = *(const bf16x8*)&Bc[r * 32 + ((kb ^ ((r >> 1) & 3)) << 3)];
    }
    __builtin_amdgcn_s_setprio(1);
#pragma unroll
    for (int m = 0; m < 4; ++m)
#pragma unroll
      for (int n = 0; n < 4; ++n)
        acc[m][n] = __builtin_amdgcn_mfma_f32_16x16x32_bf16(af[m], bf[n], acc[m][n], 0, 0, 0);
    __builtin_amdgcn_s_setprio(0);
    __builtin_amdgcn_s_barrier();           // all waves done reading cur
    asm volatile("" ::: "memory");
    cur = (cur + 1 >= 3) ? 0 : cur + 1;
  }
}

// ---------------- merged cast: x -> xb, {Wq,Wk,Wv} -> Wb ---------------------
__global__ __launch_bounds__(256) void k_cast(
    const float* __restrict__ x, const float* __restrict__ Wq,
    const float* __restrict__ Wk, const float* __restrict__ Wv,
    unsigned short* __restrict__ xb, unsigned short* __restrict__ Wb)
{
  const int bid = blockIdx.x;
  const float* src;
  unsigned short* dst;
  size_t i8;
  if (bid < 4096) {
    i8 = ((size_t)bid * 256 + threadIdx.x) * 8;
    src = x; dst = xb;
  } else {
    const size_t f = ((size_t)(bid - 4096) * 256 + threadIdx.x) * 8;
    const int z = (int)(f >> 18);                    // / (512*512)
    src = (z == 0) ? Wq : (z == 1 ? Wk : Wv);
    dst = Wb + ((size_t)z << 18);
    i8 = f & ((1u << 18) - 1);
  }
  float4 a = *(const float4*)&src[i8];
  float4 b = *(const float4*)&src[i8 + 4];
  uint4 o;
  o.x = (unsigned)f2bf(a.x) | ((unsigned)f2bf(a.y) << 16);
  o.y = (unsigned)f2bf(a.z) | ((unsigned)f2bf(a.w) << 16);
  o.z = (unsigned)f2bf(b.x) | ((unsigned)f2bf(b.y) << 16);
  o.w = (unsigned)f2bf(b.z) | ((unsigned)f2bf(b.w) << 16);
  *(uint4*)&dst[i8] = o;
}

// ---------------- K1: projections (bf16 MFMA, XCD-local m-slabs) -------------
__global__ __launch_bounds__(256) void k_proj(
    const unsigned short* __restrict__ xb, const unsigned short* __restrict__ Wb,
    unsigned short* __restrict__ PQ, unsigned short* __restrict__ PK,
    unsigned short* __restrict__ PKt, unsigned short* __restrict__ Vt,
    float* __restrict__ zsum)
{
  __shared__ unsigned short Al[3 * 128 * 32], Bl[3 * 128 * 32];
  __shared__ float zbuf[2][128];
  const int bid = blockIdx.x;
  const int xcd = bid & 7, idx = bid >> 3;            // idx in 0..191
  const int n = idx & 3, z = (idx >> 2) % 3, mloc = idx / 12;
  const int n0 = n * 128, m0 = (xcd * 16 + mloc) * 128;
  const int t = threadIdx.x, wid = t >> 6, lane = t & 63;
  const int wm = wid >> 1, wn = wid & 1;
  f32x4 acc[4][4];
  const f32x4 zero = {0.f, 0.f, 0.f, 0.f};
#pragma unroll
  for (int m = 0; m < 4; ++m)
#pragma unroll
    for (int nn = 0; nn < 4; ++nn) acc[m][nn] = zero;

  mm_loop(xb + (size_t)m0 * Cn, Cn,
          Wb + (size_t)z * Cn * Cn + (size_t)n0 * Cn, Cn, Cn / 32, Al, Bl, acc);

  float ps[4] = {0.f, 0.f, 0.f, 0.f};
#pragma unroll
  for (int m = 0; m < 4; ++m)
#pragma unroll
    for (int nn = 0; nn < 4; ++nn) {
      const int row0 = m0 + wm * 64 + m * 16 + ((lane >> 4) << 2);
      const int col  = n0 + wn * 64 + nn * 16 + (lane & 15);
      f32x4 v = acc[m][nn];
      if (z == 0) {
#pragma unroll
        for (int j = 0; j < 4; ++j)
          PQ[(size_t)(row0 + j) * Cn + col] = f2bf(phi_f(v[j]));
      } else if (z == 1) {
        ushort4 p;
#pragma unroll
        for (int j = 0; j < 4; ++j) {
          unsigned short u = f2bf(phi_f(v[j]));
          PK[(size_t)(row0 + j) * Cn + col] = u;
          (&p.x)[j] = u;
          ps[nn] += bf2f(u);
        }
        const int b = row0 >> 11, tq = row0 & (Sn - 1);
        *(ushort4*)&PKt[((size_t)b * Cn + col) * Sn + tq] = p;
      } else {
        ushort4 p;
#pragma unroll
        for (int j = 0; j < 4; ++j) (&p.x)[j] = f2bf(v[j]);
        const int b = row0 >> 11, tq = row0 & (Sn - 1);
        *(ushort4*)&Vt[((size_t)b * Cn + col) * Sn + tq] = p;
      }
    }

  if (z == 1) {   // block covers one (b, chunk) x cols n0..n0+127 completely
#pragma unroll
    for (int nn = 0; nn < 4; ++nn) {
      float v = ps[nn];
      v += __shfl_xor(v, 16); v += __shfl_xor(v, 32);   // reduce over kb
      if (lane < 16) zbuf[wm][wn * 64 + nn * 16 + lane] = v;
    }
    __syncthreads();
    if (t < 128) {
      const int b = m0 >> 11, ch = (m0 >> 7) & 15;
      zsum[((size_t)b * NCn + ch) * Cn + n0 + t] = zbuf[0][t] + zbuf[1][t];
    }
  }
}

// ---- gram staging: A 64x32 (1 load/thread), B 128x32 (2 loads/thread) -------
__device__ __forceinline__ void stageA64(const unsigned short* __restrict__ g,
                                         unsigned short* lds, int wid, int lane) {
  const int row = wid * 16 + (lane >> 2);
  const int ks  = (lane & 3) ^ ((row >> 1) & 3);
  __builtin_amdgcn_global_load_lds(
      (const __attribute__((address_space(1))) void*)(g + (size_t)row * Cn + ks * 8),
      (__attribute__((address_space(3))) void*)(lds + wid * 512), 16, 0, 0);
}
__device__ __forceinline__ void stageB128(const unsigned short* __restrict__ g,
                                          unsigned short* lds, int wid, int lane) {
#pragma unroll
  for (int e = 0; e < 2; ++e) {
    const int row = e * 64 + wid * 16 + (lane >> 2);     // FIX: was e*128
    const int ks  = (lane & 3) ^ ((row >> 1) & 3);
    __builtin_amdgcn_global_load_lds(
        (const __attribute__((address_space(1))) void*)(g + (size_t)row * Cn + ks * 8),
        (__attribute__((address_space(3))) void*)(lds + e * 2048 + wid * 512),  // FIX: was e*4096
        16, 0, 0);
  }
}

// ---------------- K2a: A = tril(PQ_c PK_c^T) bf16; scale fused ---------------
// grid (2, NC, B): block does 64 rows x 128 cols, K=512. 4 waves of 64x32
// (4m x 2n frags). Cols whole -> rowsum/scale stay block-local.
__global__ __launch_bounds__(256) void k_gram(
    const unsigned short* __restrict__ PQ, const unsigned short* __restrict__ PK,
    const float* __restrict__ zsum,
    unsigned short* __restrict__ Abuf, float* __restrict__ scale)
{
  __shared__ unsigned short Asl[3 * 2048], Bsl[3 * 4096];
  __shared__ float rsmem[4][64];
  __shared__ float zpl[512];
  const int b = blockIdx.z, ch = blockIdx.y, i0 = blockIdx.x * 64;
  const unsigned short* Aq = PQ + ((size_t)(b * Sn + ch * Tn + i0)) * Cn;
  const unsigned short* Bk = PK + ((size_t)(b * Sn + ch * Tn)) * Cn;
  const int t = threadIdx.x, wid = t >> 6, lane = t & 63;
  const int fr = lane & 15, kb = lane >> 4;
  f32x4 acc[4][2];
  const f32x4 zero = {0.f, 0.f, 0.f, 0.f};
#pragma unroll
  for (int m = 0; m < 4; ++m)
#pragma unroll
    for (int n = 0; n < 2; ++n) acc[m][n] = zero;

  stageA64(Aq, Asl, wid, lane);
  stageB128(Bk, Bsl, wid, lane);
  stageA64(Aq + 32, Asl + 2048, wid, lane);
  stageB128(Bk + 32, Bsl + 4096, wid, lane);
  int cur = 0;
  for (int kt = 0; kt < 16; ++kt) {
    if (kt + 2 < 16) {
      const int nx2 = (cur + 2 >= 3) ? cur - 1 : cur + 2;
      stageA64(Aq + (kt + 2) * 32, Asl + nx2 * 2048, wid, lane);
      stageB128(Bk + (kt + 2) * 32, Bsl + nx2 * 4096, wid, lane);
      asm volatile("s_waitcnt vmcnt(6)" ::: "memory");
    } else if (kt + 1 < 16) {
      asm volatile("s_waitcnt vmcnt(3)" ::: "memory");
    } else {
      asm volatile("s_waitcnt vmcnt(0)" ::: "memory");
    }
    __builtin_amdgcn_s_barrier();
    asm volatile("" ::: "memory");
    const unsigned short* Ac = Asl + cur * 2048;
    const unsigned short* Bc = Bsl + cur * 4096;
    bf16x8 af[4], bf[2];
#pragma unroll
    for (int m = 0; m < 4; ++m) {
      const int r = m * 16 + fr;
      af[m] = *(const bf16x8*)&Ac[r * 32 + ((kb ^ ((r >> 1) & 3)) << 3)];
    }
#pragma unroll
    for (int n = 0; n < 2; ++n) {
      const int c = wid * 32 + n * 16 + fr;
      bf[n] = *(const bf16x8*)&Bc[c * 32 + ((kb ^ ((c >> 1) & 3)) << 3)];
    }
    __builtin_amdgcn_s_setprio(1);
#pragma unroll
    for (int m = 0; m < 4; ++m)
#pragma unroll
      for (int n = 0; n < 2; ++n)
        acc[m][n] = __builtin_amdgcn_mfma_f32_16x16x32_bf16(af[m], bf[n], acc[m][n], 0, 0, 0);
    __builtin_amdgcn_s_setprio(0);
    __builtin_amdgcn_s_barrier();
    asm volatile("" ::: "memory");
    cur = (cur + 1 >= 3) ? 0 : cur + 1;
  }

  float rsum[4][4];
#pragma unroll
  for (int m = 0; m < 4; ++m)
#pragma unroll
    for (int j = 0; j < 4; ++j) rsum[m][j] = 0.f;
#pragma unroll
  for (int m = 0; m < 4; ++m)
#pragma unroll
    for (int n = 0; n < 2; ++n) {
      f32x4 v = acc[m][n];
#pragma unroll
      for (int j = 0; j < 4; ++j) {
        const int row_g = i0 + m * 16 + kb * 4 + j;     // chunk-local row
        const int col   = wid * 32 + n * 16 + fr;
        unsigned short u = (col <= row_g) ? f2bf(v[j]) : 0;
        Abuf[((size_t)(b * NCn + ch) * Tn + row_g) * Tn + col] = u;
        rsum[m][j] += bf2f(u);
      }
    }
#pragma unroll
  for (int m = 0; m < 4; ++m)
#pragma unroll
    for (int j = 0; j < 4; ++j) {
      float r = rsum[m][j];
      r += __shfl_xor(r, 1); r += __shfl_xor(r, 2);
      r += __shfl_xor(r, 4); r += __shfl_xor(r, 8);
      if (fr == 0) rsmem[wid][m * 16 + kb * 4 + j] = r;
    }
  // exclusive chunk-prefix of zsum -> zpl
#pragma unroll
  for (int e = 0; e < 2; ++e) {
    const int c = t + e * 256;
    float s = 0.f;
    for (int ch2 = 0; ch2 < ch; ++ch2)
      s += zsum[((size_t)b * NCn + ch2) * Cn + c];
    zpl[c] = s;
  }
  __syncthreads();
  // per-row dot(PQ_row, zpl): 4 threads per row, 128 cols each
  const int row = t >> 2, q4 = (t & 3) * 128;
  const unsigned short* pq = Aq + (size_t)row * Cn + q4;
  float dacc = 0.f;
  for (int i = 0; i < 128; i += 8) {
    uint4 q = *(const uint4*)(pq + i);
    dacc += bf2f((unsigned short)(q.x & 0xffff)) * zpl[q4 + i + 0]
          + bf2f((unsigned short)(q.x >> 16))    * zpl[q4 + i + 1]
          + bf2f((unsigned short)(q.y & 0xffff)) * zpl[q4 + i + 2]
          + bf2f((unsigned short)(q.y >> 16))    * zpl[q4 + i + 3]
          + bf2f((unsigned short)(q.z & 0xffff)) * zpl[q4 + i + 4]
          + bf2f((unsigned short)(q.z >> 16))    * zpl[q4 + i + 5]
          + bf2f((unsigned short)(q.w & 0xffff)) * zpl[q4 + i + 6]
          + bf2f((unsigned short)(q.w >> 16))    * zpl[q4 + i + 7];
  }
  dacc += __shfl_xor(dacc, 1);
  dacc += __shfl_xor(dacc, 2);
  if ((t & 3) == 0)
    scale[(size_t)b * Sn + ch * Tn + i0 + row] =
        rsmem[0][row] + rsmem[1][row] + rsmem[2][row] + rsmem[3][row] + dacc + 1e-5f;
}

// ---- stage a 64x128 bf16 tile global->LDS, swizzle slot ^= row&7 ------------
__device__ __forceinline__ void stage64x128(const unsigned short* __restrict__ g,
                                            int ld, unsigned short* lds,
                                            int wid, int lane) {
#pragma unroll
  for (int i = 0; i < 4; ++i) {
    const int row = wid * 16 + i * 4 + (lane >> 4);
    const int s   = (lane & 15) ^ (row & 7);
    const unsigned short* src = g + (size_t)row * ld + s * 8;
    unsigned short* dst = lds + (size_t)(wid * 16 + i * 4) * 128;   // wave-uniform
    __builtin_amdgcn_global_load_lds(
        (const __attribute__((address_space(1))) void*)src,
        (__attribute__((address_space(3))) void*)dst, 16, 0, 0);
  }
}

// ---------------- K3a: fused KV + exclusive prefix (BK=128, counted vmcnt) ---
__global__ __launch_bounds__(256) void k_kvp(
    const unsigned short* __restrict__ PKt, const unsigned short* __restrict__ Vt,
    unsigned short* __restrict__ Mpre)
{
  __shared__ unsigned short Al[2 * 64 * 128], Bl[2 * 64 * 128];
  const int bid = blockIdx.x;
  const int b = bid & 7, idx = bid >> 3;
  const int d0 = (idx & 7) * 64, c0 = (idx >> 3) * 64;
  const int t = threadIdx.x, wid = t >> 6, lane = t & 63;
  const int wm = wid >> 1, wn = wid & 1;
  const int fr = lane & 15, kb = lane >> 4;
  f32x4 acc[2][2];
  const f32x4 zero = {0.f, 0.f, 0.f, 0.f};
#pragma unroll
  for (int m = 0; m < 2; ++m)
#pragma unroll
    for (int n = 0; n < 2; ++n) acc[m][n] = zero;
  const unsigned short* Ag = PKt + ((size_t)b * Cn + c0) * Sn;
  const unsigned short* Bg = Vt  + ((size_t)b * Cn + d0) * Sn;
  stage64x128(Ag, Sn, Al, wid, lane);
  stage64x128(Bg, Sn, Bl, wid, lane);
  int cur = 0;
  for (int ch = 0; ch < NCn; ++ch) {
    const int nxt = cur ^ 1;
    if (ch + 1 < NCn) {
      stage64x128(Ag + (ch + 1) * Tn, Sn, Al + nxt * 8192, wid, lane);
      stage64x128(Bg + (ch + 1) * Tn, Sn, Bl + nxt * 8192, wid, lane);
      asm volatile("s_waitcnt vmcnt(8)" ::: "memory");
    } else {
      asm volatile("s_waitcnt vmcnt(0)" ::: "memory");
    }
    __builtin_amdgcn_s_barrier();
    asm volatile("" ::: "memory");
    if (ch > 0) {   // Mpre[ch] = sum of chunks < ch (Mpre[0] never read)
#pragma unroll
      for (int m = 0; m < 2; ++m)
#pragma unroll
        for (int n = 0; n < 2; ++n) {
          const int c_row = c0 + wm * 32 + m * 16 + (kb << 2);
          const int d     = d0 + wn * 32 + n * 16 + fr;
          ushort4 p;
#pragma unroll
          for (int j = 0; j < 4; ++j) (&p.x)[j] = f2bf(acc[m][n][j]);
          *(ushort4*)&Mpre[((size_t)(b * NCn + ch) * Cn + d) * Cn + c_row] = p;
        }
    }
    const unsigned short* Ac = Al + cur * 8192;
    const unsigned short* Bc = Bl + cur * 8192;
    __builtin_amdgcn_s_setprio(1);
#pragma unroll
    for (int kt = 0; kt < 4; ++kt) {
      bf16x8 af[2], bf[2];
#pragma unroll
      for (int m = 0; m < 2; ++m) {
        const int r = wm * 32 + m * 16 + fr;
        af[m] = *(const bf16x8*)&Ac[r * 128 + (((kt * 4 + kb) ^ (r & 7)) << 3)];
      }
#pragma unroll
      for (int n = 0; n < 2; ++n) {
        const int r = wn * 32 + n * 16 + fr;
        bf[n] = *(const bf16x8*)&Bc[r * 128 + (((kt * 4 + kb) ^ (r & 7)) << 3)];
      }
#pragma unroll
      for (int m = 0; m < 2; ++m)
#pragma unroll
        for (int n = 0; n < 2; ++n)
          acc[m][n] = __builtin_amdgcn_mfma_f32_16x16x32_bf16(af[m], bf[n], acc[m][n], 0, 0, 0);
    }
    __builtin_amdgcn_s_setprio(0);
    __builtin_amdgcn_s_barrier();
    asm volatile("" ::: "memory");
    cur = nxt;
  }
}

// ---------------- K3b: out = (A@V_c + PQ_c@Mpre_c) / scale -------------------
// Single fused 20-step pipelined K-loop (intra kt<4, inter kt>=4).
__global__ __launch_bounds__(256) void k_avinter(
    const unsigned short* __restrict__ Abuf, const unsigned short* __restrict__ Vt,
    const unsigned short* __restrict__ PQ, const unsigned short* __restrict__ Mpre,
    const float* __restrict__ scale, float* __restrict__ out)
{
  __shared__ unsigned short Al[3 * 128 * 32], Bl[3 * 128 * 32];
  const int bid = blockIdx.x;
  const int logical = (bid & 7) * 64 + (bid >> 3);
  const int d0 = (logical & 3) * 128;
  const int ch = (logical >> 2) & 15;
  const int b  = logical >> 6;
  const int t0 = ch * Tn;
  const int t = threadIdx.x, wid = t >> 6, lane = t & 63;
  const int wm = wid >> 1, wn = wid & 1;
  const int fr = lane & 15, kb = lane >> 4;
  f32x4 acc[4][4];
  const f32x4 zero = {0.f, 0.f, 0.f, 0.f};
#pragma unroll
  for (int m = 0; m < 4; ++m)
#pragma unroll
    for (int n = 0; n < 4; ++n) acc[m][n] = zero;

  const unsigned short* Aintra = Abuf + (size_t)(b * NCn + ch) * Tn * Tn;
  const unsigned short* Bintra = Vt + ((size_t)b * Cn + d0) * Sn + t0;
  const unsigned short* Ainter = PQ + ((size_t)b * Sn + t0) * Cn;
  const unsigned short* Binter = Mpre + ((size_t)(b * NCn + ch) * Cn + d0) * Cn;
  auto srcA = [&](int kt) { return (kt < 4) ? Aintra + kt * 32 : Ainter + (kt - 4) * 32; };
  auto srcB = [&](int kt) { return (kt < 4) ? Bintra + kt * 32 : Binter + (kt - 4) * 32; };
  auto ldA  = [&](int kt) { return (kt < 4) ? Tn : Cn; };
  auto ldB  = [&](int kt) { return (kt < 4) ? Sn : Cn; };
  const int nkt = (ch > 0) ? 20 : 4;

  stage128x32(srcA(0), ldA(0), Al, wid, lane);
  stage128x32(srcB(0), ldB(0), Bl, wid, lane);
  stage128x32(srcA(1), ldA(1), Al + 4096, wid, lane);
  stage128x32(srcB(1), ldB(1), Bl + 4096, wid, lane);
  int cur = 0;
  for (int kt = 0; kt < nkt; ++kt) {
    if (kt + 2 < nkt) {
      const int nx2 = (cur + 2 >= 3) ? cur - 1 : cur + 2;
      stage128x32(srcA(kt + 2), ldA(kt + 2), Al + nx2 * 4096, wid, lane);
      stage128x32(srcB(kt + 2), ldB(kt + 2), Bl + nx2 * 4096, wid, lane);
      asm volatile("s_waitcnt vmcnt(8)" ::: "memory");
    } else if (kt + 1 < nkt) {
      asm volatile("s_waitcnt vmcnt(4)" ::: "memory");
    } else {
      asm volatile("s_waitcnt vmcnt(0)" ::: "memory");
    }
    __builtin_amdgcn_s_barrier();
    asm volatile("" ::: "memory");
    const unsigned short* Ac = Al + cur * 4096;
    const unsigned short* Bc = Bl + cur * 4096;
    bf16x8 af[4], bf[4];
#pragma unroll
    for (int m = 0; m < 4; ++m) {
      const int r = wm * 64 + m * 16 + fr;
      af[m] = *(const bf16x8*)&Ac[r * 32 + ((kb ^ ((r >> 1) & 3)) << 3)];
    }
#pragma unroll
    for (int n = 0; n < 4; ++n) {
      const int r = wn * 64 + n * 16 + fr;
      bf[n] = *(const bf16x8*)&Bc[r * 32 + ((kb ^ ((r >> 1) & 3)) << 3)];
    }
    __builtin_amdgcn_s_setprio(1);
#pragma unroll
    for (int m = 0; m < 4; ++m)
#pragma unroll
      for (int n = 0; n < 4; ++n)
        acc[m][n] = __builtin_amdgcn_mfma_f32_16x16x32_bf16(af[m], bf[n], acc[m][n], 0, 0, 0);
    __builtin_amdgcn_s_setprio(0);
    __builtin_amdgcn_s_barrier();
    asm volatile("" ::: "memory");
    cur = (cur + 1 >= 3) ? 0 : cur + 1;
  }

#pragma unroll
  for (int m = 0; m < 4; ++m)
#pragma unroll
    for (int n = 0; n < 4; ++n) {
      const int row0 = t0 + wm * 64 + m * 16 + ((lane >> 4) << 2);
      const int col  = d0 + wn * 64 + n * 16 + (lane & 15);
      f32x4 v = acc[m][n];
#pragma unroll
      for (int j = 0; j < 4; ++j) {
        const size_t sidx = (size_t)b * Sn + row0 + j;
        out[sidx * Cn + col] = v[j] / scale[sidx];
      }
    }
}

// ---------------- launch -----------------------------------------------------
extern "C" void kernel_launch(void* const* d_in, const int* in_sizes, int n_in,
                              void* d_out, int out_size, void* d_ws, size_t ws_size,
                              hipStream_t stream)
{
  const float* x  = (const float*)d_in[0];
  const float* Wq = (const float*)d_in[1];
  const float* Wk = (const float*)d_in[2];
  const float* Wv = (const float*)d_in[3];
  float* out = (float*)d_out;

  unsigned short* xb   = (unsigned short*)d_ws;
  unsigned short* Wb   = xb   + (size_t)Bn * Sn * Cn;          // 8.39M
  unsigned short* PQ   = Wb   + (size_t)3 * Cn * Cn;           // 0.79M
  unsigned short* PK   = PQ   + (size_t)Bn * Sn * Cn;
  unsigned short* PKt  = PK   + (size_t)Bn * Sn * Cn;
  unsigned short* Vt   = PKt  + (size_t)Bn * Sn * Cn;
  unsigned short* Abuf = Vt   + (size_t)Bn * Sn * Cn;          // 2.10M
  unsigned short* Mpre = Abuf + (size_t)Bn * NCn * Tn * Tn;    // 33.55M
  float* scale = (float*)(Mpre + (size_t)Bn * NCn * Cn * Cn);  // 16K
  float* zsum  = scale + (size_t)Bn * Sn;                      // 64K
  (void)ws_size; (void)in_sizes; (void)n_in; (void)out_size;

  hipLaunchKernelGGL(k_cast, dim3(4096 + 384), dim3(256), 0, stream, x, Wq, Wk, Wv, xb, Wb);
  hipLaunchKernelGGL(k_proj, dim3(1536), dim3(256), 0, stream, xb, Wb, PQ, PK, PKt, Vt, zsum);
  hipLaunchKernelGGL(k_gram, dim3(2, NCn, Bn), dim3(256), 0, stream, PQ, PK, zsum, Abuf, scale);
  hipLaunchKernelGGL(k_kvp, dim3(512), dim3(256), 0, stream, PKt, Vt, Mpre);
  hipLaunchKernelGGL(k_avinter, dim3(512), dim3(256), 0, stream, Abuf, Vt, PQ, Mpre, scale, out);
}

// Round 13
// 124.941 us; speedup vs baseline: 1.2032x; 1.0011x over previous
//
#include <hip/hip_runtime.h>

// LinearAttentionCell: chunked linear attention, bf16 MFMA.
// R13 = R12 + (a) proj 256x128 tile / 512 threads (8 waves, 2x waves/CU),
//             (b) gram+kvp merged into one launch (kvp blocks first).

constexpr int Bn  = 8;
constexpr int Sn  = 2048;
constexpr int Cn  = 512;
constexpr int Tn  = 128;
constexpr int NCn = 16;
constexpr float DKf = 0.04419417382415922f;     // 1/sqrt(512)

typedef __attribute__((ext_vector_type(8))) short bf16x8;
typedef __attribute__((ext_vector_type(4))) float f32x4;

__device__ __forceinline__ unsigned short f2bf(float f) {   // RNE
  unsigned u = __float_as_uint(f);
  u = (u + 0x7fffu + ((u >> 16) & 1u)) >> 16;
  return (unsigned short)u;
}
__device__ __forceinline__ float bf2f(unsigned short h) {
  return __uint_as_float(((unsigned)h) << 16);
}
__device__ __forceinline__ float phi_f(float u) {
  float s = u * DKf;
  return s > 0.0f ? s + 1.0f : __expf(s);       // elu(s)+1
}

// ---------------- merged cast: x -> xb, {Wq,Wk,Wv} -> Wb ---------------------
__global__ __launch_bounds__(256) void k_cast(
    const float* __restrict__ x, const float* __restrict__ Wq,
    const float* __restrict__ Wk, const float* __restrict__ Wv,
    unsigned short* __restrict__ xb, unsigned short* __restrict__ Wb)
{
  const int bid = blockIdx.x;
  const float* src;
  unsigned short* dst;
  size_t i8;
  if (bid < 4096) {
    i8 = ((size_t)bid * 256 + threadIdx.x) * 8;
    src = x; dst = xb;
  } else {
    const size_t f = ((size_t)(bid - 4096) * 256 + threadIdx.x) * 8;
    const int z = (int)(f >> 18);                    // / (512*512)
    src = (z == 0) ? Wq : (z == 1 ? Wk : Wv);
    dst = Wb + ((size_t)z << 18);
    i8 = f & ((1u << 18) - 1);
  }
  float4 a = *(const float4*)&src[i8];
  float4 b = *(const float4*)&src[i8 + 4];
  uint4 o;
  o.x = (unsigned)f2bf(a.x) | ((unsigned)f2bf(a.y) << 16);
  o.y = (unsigned)f2bf(a.z) | ((unsigned)f2bf(a.w) << 16);
  o.z = (unsigned)f2bf(b.x) | ((unsigned)f2bf(b.y) << 16);
  o.w = (unsigned)f2bf(b.z) | ((unsigned)f2bf(b.w) << 16);
  *(uint4*)&dst[i8] = o;
}

// ---- proj staging (512 threads): A 256x32 (2 loads/thr), B 128x32 (1) -------
__device__ __forceinline__ void stageA256(const unsigned short* __restrict__ g,
                                          unsigned short* lds, int wid, int lane) {
#pragma unroll
  for (int cc = 0; cc < 2; ++cc) {
    const int row = cc * 128 + wid * 16 + (lane >> 2);
    const int ks  = (lane & 3) ^ ((row >> 1) & 3);
    __builtin_amdgcn_global_load_lds(
        (const __attribute__((address_space(1))) void*)(g + (size_t)row * Cn + ks * 8),
        (__attribute__((address_space(3))) void*)(lds + (cc * 128 + wid * 16) * 32),
        16, 0, 0);
  }
}
__device__ __forceinline__ void stageB128w8(const unsigned short* __restrict__ g,
                                            unsigned short* lds, int wid, int lane) {
  const int row = wid * 16 + (lane >> 2);
  const int ks  = (lane & 3) ^ ((row >> 1) & 3);
  __builtin_amdgcn_global_load_lds(
      (const __attribute__((address_space(1))) void*)(g + (size_t)row * Cn + ks * 8),
      (__attribute__((address_space(3))) void*)(lds + (wid * 16) * 32), 16, 0, 0);
}

// ---------------- K1: projections, 256x128 tile, 8 waves (4m x 2n) -----------
// 768 blocks: xcd = bid&7 owns 8 contiguous 256-row m-slabs x 4 n x 3 z.
// z==1 blocks also emit zsum for their TWO chunks.
__global__ __launch_bounds__(512) void k_proj(
    const unsigned short* __restrict__ xb, const unsigned short* __restrict__ Wb,
    unsigned short* __restrict__ PQ, unsigned short* __restrict__ PK,
    unsigned short* __restrict__ PKt, unsigned short* __restrict__ Vt,
    float* __restrict__ zsum)
{
  __shared__ unsigned short Al[3 * 8192], Bl[3 * 4096];   // 48 KB + 24 KB
  __shared__ float zbuf[4][128];
  const int bid = blockIdx.x;
  const int xcd = bid & 7, idx = bid >> 3;            // idx 0..95
  const int n = idx & 3, z = (idx >> 2) % 3, mloc = idx / 12;   // mloc 0..7
  const int n0 = n * 128, m0 = (xcd * 8 + mloc) * 256;
  const int t = threadIdx.x, wid = t >> 6, lane = t & 63;
  const int wm = wid >> 1, wn = wid & 1;              // 4m x 2n
  const int fr = lane & 15, kb = lane >> 4;
  f32x4 acc[4][4];
  const f32x4 zero = {0.f, 0.f, 0.f, 0.f};
#pragma unroll
  for (int m = 0; m < 4; ++m)
#pragma unroll
    for (int nn = 0; nn < 4; ++nn) acc[m][nn] = zero;

  const unsigned short* Ag = xb + (size_t)m0 * Cn;
  const unsigned short* Bg = Wb + (size_t)z * Cn * Cn + (size_t)n0 * Cn;

  stageA256(Ag, Al, wid, lane);
  stageB128w8(Bg, Bl, wid, lane);
  stageA256(Ag + 32, Al + 8192, wid, lane);
  stageB128w8(Bg + 32, Bl + 4096, wid, lane);
  int cur = 0;
  for (int kt = 0; kt < 16; ++kt) {
    if (kt + 2 < 16) {
      const int nx2 = (cur + 2 >= 3) ? cur - 1 : cur + 2;
      stageA256(Ag + (kt + 2) * 32, Al + nx2 * 8192, wid, lane);
      stageB128w8(Bg + (kt + 2) * 32, Bl + nx2 * 4096, wid, lane);
      asm volatile("s_waitcnt vmcnt(6)" ::: "memory");
    } else if (kt + 1 < 16) {
      asm volatile("s_waitcnt vmcnt(3)" ::: "memory");
    } else {
      asm volatile("s_waitcnt vmcnt(0)" ::: "memory");
    }
    __builtin_amdgcn_s_barrier();
    asm volatile("" ::: "memory");
    const unsigned short* Ac = Al + cur * 8192;
    const unsigned short* Bc = Bl + cur * 4096;
    bf16x8 af[4], bf[4];
#pragma unroll
    for (int m = 0; m < 4; ++m) {
      const int r = wm * 64 + m * 16 + fr;
      af[m] = *(const bf16x8*)&Ac[r * 32 + ((kb ^ ((r >> 1) & 3)) << 3)];
    }
#pragma unroll
    for (int nn = 0; nn < 4; ++nn) {
      const int r = wn * 64 + nn * 16 + fr;
      bf[nn] = *(const bf16x8*)&Bc[r * 32 + ((kb ^ ((r >> 1) & 3)) << 3)];
    }
    __builtin_amdgcn_s_setprio(1);
#pragma unroll
    for (int m = 0; m < 4; ++m)
#pragma unroll
      for (int nn = 0; nn < 4; ++nn)
        acc[m][nn] = __builtin_amdgcn_mfma_f32_16x16x32_bf16(af[m], bf[nn], acc[m][nn], 0, 0, 0);
    __builtin_amdgcn_s_setprio(0);
    __builtin_amdgcn_s_barrier();
    asm volatile("" ::: "memory");
    cur = (cur + 1 >= 3) ? 0 : cur + 1;
  }

  float ps[4] = {0.f, 0.f, 0.f, 0.f};
#pragma unroll
  for (int m = 0; m < 4; ++m)
#pragma unroll
    for (int nn = 0; nn < 4; ++nn) {
      const int row0 = m0 + wm * 64 + m * 16 + ((lane >> 4) << 2);
      const int col  = n0 + wn * 64 + nn * 16 + fr;
      f32x4 v = acc[m][nn];
      if (z == 0) {
#pragma unroll
        for (int j = 0; j < 4; ++j)
          PQ[(size_t)(row0 + j) * Cn + col] = f2bf(phi_f(v[j]));
      } else if (z == 1) {
        ushort4 p;
#pragma unroll
        for (int j = 0; j < 4; ++j) {
          unsigned short u = f2bf(phi_f(v[j]));
          PK[(size_t)(row0 + j) * Cn + col] = u;
          (&p.x)[j] = u;
          ps[nn] += bf2f(u);
        }
        const int b = row0 >> 11, tq = row0 & (Sn - 1);
        *(ushort4*)&PKt[((size_t)b * Cn + col) * Sn + tq] = p;
      } else {
        ushort4 p;
#pragma unroll
        for (int j = 0; j < 4; ++j) (&p.x)[j] = f2bf(v[j]);
        const int b = row0 >> 11, tq = row0 & (Sn - 1);
        *(ushort4*)&Vt[((size_t)b * Cn + col) * Sn + tq] = p;
      }
    }

  if (z == 1) {   // block covers (b, ch0) and (b, ch0+1), cols n0..n0+127
#pragma unroll
    for (int nn = 0; nn < 4; ++nn) {
      float v = ps[nn];
      v += __shfl_xor(v, 16); v += __shfl_xor(v, 32);   // reduce over kb
      if (lane < 16) zbuf[wm][wn * 64 + nn * 16 + lane] = v;
    }
    __syncthreads();
    if (t < 256) {
      const int c = t >> 7, colI = t & 127;
      const int b = m0 >> 11, ch = ((m0 >> 7) & 15) + c;
      zsum[((size_t)b * NCn + ch) * Cn + n0 + colI] =
          zbuf[2 * c][colI] + zbuf[2 * c + 1][colI];
    }
  }
}

// ---- gram staging: A 64x32 (1 load/thread), B 128x32 (2 loads/thread) -------
__device__ __forceinline__ void stageA64(const unsigned short* __restrict__ g,
                                         unsigned short* lds, int wid, int lane) {
  const int row = wid * 16 + (lane >> 2);
  const int ks  = (lane & 3) ^ ((row >> 1) & 3);
  __builtin_amdgcn_global_load_lds(
      (const __attribute__((address_space(1))) void*)(g + (size_t)row * Cn + ks * 8),
      (__attribute__((address_space(3))) void*)(lds + wid * 512), 16, 0, 0);
}
__device__ __forceinline__ void stageB128(const unsigned short* __restrict__ g,
                                          unsigned short* lds, int wid, int lane) {
#pragma unroll
  for (int e = 0; e < 2; ++e) {
    const int row = e * 64 + wid * 16 + (lane >> 2);
    const int ks  = (lane & 3) ^ ((row >> 1) & 3);
    __builtin_amdgcn_global_load_lds(
        (const __attribute__((address_space(1))) void*)(g + (size_t)row * Cn + ks * 8),
        (__attribute__((address_space(3))) void*)(lds + e * 2048 + wid * 512),
        16, 0, 0);
  }
}

// ---- stage a 64x128 bf16 tile global->LDS, swizzle slot ^= row&7 ------------
__device__ __forceinline__ void stage64x128(const unsigned short* __restrict__ g,
                                            int ld, unsigned short* lds,
                                            int wid, int lane) {
#pragma unroll
  for (int i = 0; i < 4; ++i) {
    const int row = wid * 16 + i * 4 + (lane >> 4);
    const int s   = (lane & 15) ^ (row & 7);
    const unsigned short* src = g + (size_t)row * ld + s * 8;
    unsigned short* dst = lds + (size_t)(wid * 16 + i * 4) * 128;   // wave-uniform
    __builtin_amdgcn_global_load_lds(
        (const __attribute__((address_space(1))) void*)src,
        (__attribute__((address_space(3))) void*)dst, 16, 0, 0);
  }
}

// ---------------- K2: merged gram (blocks 512..767) + kvp (blocks 0..511) ----
// Independent inputs/outputs; kvp (long pole) dispatches first, gram fills in.
__global__ __launch_bounds__(256) void k_gk(
    const unsigned short* __restrict__ PQ, const unsigned short* __restrict__ PK,
    const float* __restrict__ zsum,
    unsigned short* __restrict__ Abuf, float* __restrict__ scale,
    const unsigned short* __restrict__ PKt, const unsigned short* __restrict__ Vt,
    unsigned short* __restrict__ Mpre)
{
  __shared__ unsigned short smem[32768];   // 64 KB union
  const int t = threadIdx.x, wid = t >> 6, lane = t & 63;
  const int fr = lane & 15, kb = lane >> 4;
  const f32x4 zero = {0.f, 0.f, 0.f, 0.f};

  if (blockIdx.x < 512) {
    // ---------------- kvp: KV + exclusive prefix (BK=128) -------------------
    unsigned short* Al = smem;                  // 2 x 8192
    unsigned short* Bl = smem + 16384;          // 2 x 8192
    const int bid = blockIdx.x;
    const int b = bid & 7, idx = bid >> 3;
    const int d0 = (idx & 7) * 64, c0 = (idx >> 3) * 64;
    const int wm = wid >> 1, wn = wid & 1;
    f32x4 acc[2][2];
#pragma unroll
    for (int m = 0; m < 2; ++m)
#pragma unroll
      for (int n = 0; n < 2; ++n) acc[m][n] = zero;
    const unsigned short* Ag = PKt + ((size_t)b * Cn + c0) * Sn;
    const unsigned short* Bg = Vt  + ((size_t)b * Cn + d0) * Sn;
    stage64x128(Ag, Sn, Al, wid, lane);
    stage64x128(Bg, Sn, Bl, wid, lane);
    int cur = 0;
    for (int ch = 0; ch < NCn; ++ch) {
      const int nxt = cur ^ 1;
      if (ch + 1 < NCn) {
        stage64x128(Ag + (ch + 1) * Tn, Sn, Al + nxt * 8192, wid, lane);
        stage64x128(Bg + (ch + 1) * Tn, Sn, Bl + nxt * 8192, wid, lane);
        asm volatile("s_waitcnt vmcnt(8)" ::: "memory");
      } else {
        asm volatile("s_waitcnt vmcnt(0)" ::: "memory");
      }
      __builtin_amdgcn_s_barrier();
      asm volatile("" ::: "memory");
      if (ch > 0) {
#pragma unroll
        for (int m = 0; m < 2; ++m)
#pragma unroll
          for (int n = 0; n < 2; ++n) {
            const int c_row = c0 + wm * 32 + m * 16 + (kb << 2);
            const int d     = d0 + wn * 32 + n * 16 + fr;
            ushort4 p;
#pragma unroll
            for (int j = 0; j < 4; ++j) (&p.x)[j] = f2bf(acc[m][n][j]);
            *(ushort4*)&Mpre[((size_t)(b * NCn + ch) * Cn + d) * Cn + c_row] = p;
          }
      }
      const unsigned short* Ac = Al + cur * 8192;
      const unsigned short* Bc = Bl + cur * 8192;
      __builtin_amdgcn_s_setprio(1);
#pragma unroll
      for (int kt = 0; kt < 4; ++kt) {
        bf16x8 af[2], bf[2];
#pragma unroll
        for (int m = 0; m < 2; ++m) {
          const int r = wm * 32 + m * 16 + fr;
          af[m] = *(const bf16x8*)&Ac[r * 128 + (((kt * 4 + kb) ^ (r & 7)) << 3)];
        }
#pragma unroll
        for (int n = 0; n < 2; ++n) {
          const int r = wn * 32 + n * 16 + fr;
          bf[n] = *(const bf16x8*)&Bc[r * 128 + (((kt * 4 + kb) ^ (r & 7)) << 3)];
        }
#pragma unroll
        for (int m = 0; m < 2; ++m)
#pragma unroll
          for (int n = 0; n < 2; ++n)
            acc[m][n] = __builtin_amdgcn_mfma_f32_16x16x32_bf16(af[m], bf[n], acc[m][n], 0, 0, 0);
      }
      __builtin_amdgcn_s_setprio(0);
      __builtin_amdgcn_s_barrier();
      asm volatile("" ::: "memory");
      cur = nxt;
    }
  } else {
    // ---------------- gram: A = tril(PQ_c PK_c^T), scale fused --------------
    unsigned short* Asl = smem;                 // 3 x 2048
    unsigned short* Bsl = smem + 6144;          // 3 x 4096
    float* rsmem = (float*)(smem + 18432);      // [4][64]
    float* zpl   = rsmem + 256;                 // [512]
    const int g = blockIdx.x - 512;
    const int i0 = (g & 1) * 64, ch = (g >> 1) & 15, b = g >> 5;
    const unsigned short* Aq = PQ + ((size_t)(b * Sn + ch * Tn + i0)) * Cn;
    const unsigned short* Bk = PK + ((size_t)(b * Sn + ch * Tn)) * Cn;
    f32x4 acc[4][2];
#pragma unroll
    for (int m = 0; m < 4; ++m)
#pragma unroll
      for (int n = 0; n < 2; ++n) acc[m][n] = zero;

    stageA64(Aq, Asl, wid, lane);
    stageB128(Bk, Bsl, wid, lane);
    stageA64(Aq + 32, Asl + 2048, wid, lane);
    stageB128(Bk + 32, Bsl + 4096, wid, lane);
    int cur = 0;
    for (int kt = 0; kt < 16; ++kt) {
      if (kt + 2 < 16) {
        const int nx2 = (cur + 2 >= 3) ? cur - 1 : cur + 2;
        stageA64(Aq + (kt + 2) * 32, Asl + nx2 * 2048, wid, lane);
        stageB128(Bk + (kt + 2) * 32, Bsl + nx2 * 4096, wid, lane);
        asm volatile("s_waitcnt vmcnt(6)" ::: "memory");
      } else if (kt + 1 < 16) {
        asm volatile("s_waitcnt vmcnt(3)" ::: "memory");
      } else {
        asm volatile("s_waitcnt vmcnt(0)" ::: "memory");
      }
      __builtin_amdgcn_s_barrier();
      asm volatile("" ::: "memory");
      const unsigned short* Ac = Asl + cur * 2048;
      const unsigned short* Bc = Bsl + cur * 4096;
      bf16x8 af[4], bf[2];
#pragma unroll
      for (int m = 0; m < 4; ++m) {
        const int r = m * 16 + fr;
        af[m] = *(const bf16x8*)&Ac[r * 32 + ((kb ^ ((r >> 1) & 3)) << 3)];
      }
#pragma unroll
      for (int n = 0; n < 2; ++n) {
        const int c = wid * 32 + n * 16 + fr;
        bf[n] = *(const bf16x8*)&Bc[c * 32 + ((kb ^ ((c >> 1) & 3)) << 3)];
      }
      __builtin_amdgcn_s_setprio(1);
#pragma unroll
      for (int m = 0; m < 4; ++m)
#pragma unroll
        for (int n = 0; n < 2; ++n)
          acc[m][n] = __builtin_amdgcn_mfma_f32_16x16x32_bf16(af[m], bf[n], acc[m][n], 0, 0, 0);
      __builtin_amdgcn_s_setprio(0);
      __builtin_amdgcn_s_barrier();
      asm volatile("" ::: "memory");
      cur = (cur + 1 >= 3) ? 0 : cur + 1;
    }

    float rsum[4][4];
#pragma unroll
    for (int m = 0; m < 4; ++m)
#pragma unroll
      for (int j = 0; j < 4; ++j) rsum[m][j] = 0.f;
#pragma unroll
    for (int m = 0; m < 4; ++m)
#pragma unroll
      for (int n = 0; n < 2; ++n) {
        f32x4 v = acc[m][n];
#pragma unroll
        for (int j = 0; j < 4; ++j) {
          const int row_g = i0 + m * 16 + kb * 4 + j;     // chunk-local row
          const int col   = wid * 32 + n * 16 + fr;
          unsigned short u = (col <= row_g) ? f2bf(v[j]) : 0;
          Abuf[((size_t)(b * NCn + ch) * Tn + row_g) * Tn + col] = u;
          rsum[m][j] += bf2f(u);
        }
      }
#pragma unroll
    for (int m = 0; m < 4; ++m)
#pragma unroll
      for (int j = 0; j < 4; ++j) {
        float r = rsum[m][j];
        r += __shfl_xor(r, 1); r += __shfl_xor(r, 2);
        r += __shfl_xor(r, 4); r += __shfl_xor(r, 8);
        if (fr == 0) rsmem[wid * 64 + m * 16 + kb * 4 + j] = r;
      }
    // exclusive chunk-prefix of zsum -> zpl
#pragma unroll
    for (int e = 0; e < 2; ++e) {
      const int c = t + e * 256;
      float s = 0.f;
      for (int ch2 = 0; ch2 < ch; ++ch2)
        s += zsum[((size_t)b * NCn + ch2) * Cn + c];
      zpl[c] = s;
    }
    __syncthreads();
    // per-row dot(PQ_row, zpl): 4 threads per row, 128 cols each
    const int row = t >> 2, q4 = (t & 3) * 128;
    const unsigned short* pq = Aq + (size_t)row * Cn + q4;
    float dacc = 0.f;
    for (int i = 0; i < 128; i += 8) {
      uint4 q = *(const uint4*)(pq + i);
      dacc += bf2f((unsigned short)(q.x & 0xffff)) * zpl[q4 + i + 0]
            + bf2f((unsigned short)(q.x >> 16))    * zpl[q4 + i + 1]
            + bf2f((unsigned short)(q.y & 0xffff)) * zpl[q4 + i + 2]
            + bf2f((unsigned short)(q.y >> 16))    * zpl[q4 + i + 3]
            + bf2f((unsigned short)(q.z & 0xffff)) * zpl[q4 + i + 4]
            + bf2f((unsigned short)(q.z >> 16))    * zpl[q4 + i + 5]
            + bf2f((unsigned short)(q.w & 0xffff)) * zpl[q4 + i + 6]
            + bf2f((unsigned short)(q.w >> 16))    * zpl[q4 + i + 7];
    }
    dacc += __shfl_xor(dacc, 1);
    dacc += __shfl_xor(dacc, 2);
    if ((t & 3) == 0)
      scale[(size_t)b * Sn + ch * Tn + i0 + row] =
          rsmem[0 * 64 + row] + rsmem[1 * 64 + row] +
          rsmem[2 * 64 + row] + rsmem[3 * 64 + row] + dacc + 1e-5f;
  }
}

// ---- stage a 128x32 bf16 tile global->LDS (256 thr), kslot ^= (row>>1)&3 ----
__device__ __forceinline__ void stage128x32(const unsigned short* __restrict__ g,
                                            int ld, unsigned short* lds,
                                            int wid, int lane) {
#pragma unroll
  for (int cc = 0; cc < 2; ++cc) {
    const int row = cc * 64 + wid * 16 + (lane >> 2);
    const int ks  = (lane & 3) ^ ((row >> 1) & 3);
    const unsigned short* src = g + (size_t)row * ld + ks * 8;
    unsigned short* dst = lds + (size_t)(cc * 256 + wid * 64) * 8;  // wave-uniform
    __builtin_amdgcn_global_load_lds(
        (const __attribute__((address_space(1))) void*)src,
        (__attribute__((address_space(3))) void*)dst, 16, 0, 0);
  }
}

// ---------------- K3: out = (A@V_c + PQ_c@Mpre_c) / scale --------------------
// Single fused 20-step pipelined K-loop (intra kt<4, inter kt>=4).
__global__ __launch_bounds__(256) void k_avinter(
    const unsigned short* __restrict__ Abuf, const unsigned short* __restrict__ Vt,
    const unsigned short* __restrict__ PQ, const unsigned short* __restrict__ Mpre,
    const float* __restrict__ scale, float* __restrict__ out)
{
  __shared__ unsigned short Al[3 * 128 * 32], Bl[3 * 128 * 32];
  const int bid = blockIdx.x;
  const int logical = (bid & 7) * 64 + (bid >> 3);
  const int d0 = (logical & 3) * 128;
  const int ch = (logical >> 2) & 15;
  const int b  = logical >> 6;
  const int t0 = ch * Tn;
  const int t = threadIdx.x, wid = t >> 6, lane = t & 63;
  const int wm = wid >> 1, wn = wid & 1;
  const int fr = lane & 15, kb = lane >> 4;
  f32x4 acc[4][4];
  const f32x4 zero = {0.f, 0.f, 0.f, 0.f};
#pragma unroll
  for (int m = 0; m < 4; ++m)
#pragma unroll
    for (int n = 0; n < 4; ++n) acc[m][n] = zero;

  const unsigned short* Aintra = Abuf + (size_t)(b * NCn + ch) * Tn * Tn;
  const unsigned short* Bintra = Vt + ((size_t)b * Cn + d0) * Sn + t0;
  const unsigned short* Ainter = PQ + ((size_t)b * Sn + t0) * Cn;
  const unsigned short* Binter = Mpre + ((size_t)(b * NCn + ch) * Cn + d0) * Cn;
  auto srcA = [&](int kt) { return (kt < 4) ? Aintra + kt * 32 : Ainter + (kt - 4) * 32; };
  auto srcB = [&](int kt) { return (kt < 4) ? Bintra + kt * 32 : Binter + (kt - 4) * 32; };
  auto ldA  = [&](int kt) { return (kt < 4) ? Tn : Cn; };
  auto ldB  = [&](int kt) { return (kt < 4) ? Sn : Cn; };
  const int nkt = (ch > 0) ? 20 : 4;

  stage128x32(srcA(0), ldA(0), Al, wid, lane);
  stage128x32(srcB(0), ldB(0), Bl, wid, lane);
  stage128x32(srcA(1), ldA(1), Al + 4096, wid, lane);
  stage128x32(srcB(1), ldB(1), Bl + 4096, wid, lane);
  int cur = 0;
  for (int kt = 0; kt < nkt; ++kt) {
    if (kt + 2 < nkt) {
      const int nx2 = (cur + 2 >= 3) ? cur - 1 : cur + 2;
      stage128x32(srcA(kt + 2), ldA(kt + 2), Al + nx2 * 4096, wid, lane);
      stage128x32(srcB(kt + 2), ldB(kt + 2), Bl + nx2 * 4096, wid, lane);
      asm volatile("s_waitcnt vmcnt(8)" ::: "memory");
    } else if (kt + 1 < nkt) {
      asm volatile("s_waitcnt vmcnt(4)" ::: "memory");
    } else {
      asm volatile("s_waitcnt vmcnt(0)" ::: "memory");
    }
    __builtin_amdgcn_s_barrier();
    asm volatile("" ::: "memory");
    const unsigned short* Ac = Al + cur * 4096;
    const unsigned short* Bc = Bl + cur * 4096;
    bf16x8 af[4], bf[4];
#pragma unroll
    for (int m = 0; m < 4; ++m) {
      const int r = wm * 64 + m * 16 + fr;
      af[m] = *(const bf16x8*)&Ac[r * 32 + ((kb ^ ((r >> 1) & 3)) << 3)];
    }
#pragma unroll
    for (int n = 0; n < 4; ++n) {
      const int r = wn * 64 + n * 16 + fr;
      bf[n] = *(const bf16x8*)&Bc[r * 32 + ((kb ^ ((r >> 1) & 3)) << 3)];
    }
    __builtin_amdgcn_s_setprio(1);
#pragma unroll
    for (int m = 0; m < 4; ++m)
#pragma unroll
      for (int n = 0; n < 4; ++n)
        acc[m][n] = __builtin_amdgcn_mfma_f32_16x16x32_bf16(af[m], bf[n], acc[m][n], 0, 0, 0);
    __builtin_amdgcn_s_setprio(0);
    __builtin_amdgcn_s_barrier();
    asm volatile("" ::: "memory");
    cur = (cur + 1 >= 3) ? 0 : cur + 1;
  }

#pragma unroll
  for (int m = 0; m < 4; ++m)
#pragma unroll
    for (int n = 0; n < 4; ++n) {
      const int row0 = t0 + wm * 64 + m * 16 + ((lane >> 4) << 2);
      const int col  = d0 + wn * 64 + n * 16 + (lane & 15);
      f32x4 v = acc[m][n];
#pragma unroll
      for (int j = 0; j < 4; ++j) {
        const size_t sidx = (size_t)b * Sn + row0 + j;
        out[sidx * Cn + col] = v[j] / scale[sidx];
      }
    }
}

// ---------------- launch -----------------------------------------------------
extern "C" void kernel_launch(void* const* d_in, const int* in_sizes, int n_in,
                              void* d_out, int out_size, void* d_ws, size_t ws_size,
                              hipStream_t stream)
{
  const float* x  = (const float*)d_in[0];
  const float* Wq = (const float*)d_in[1];
  const float* Wk = (const float*)d_in[2];
  const float* Wv = (const float*)d_in[3];
  float* out = (float*)d_out;

  unsigned short* xb   = (unsigned short*)d_ws;
  unsigned short* Wb   = xb   + (size_t)Bn * Sn * Cn;          // 8.39M
  unsigned short* PQ   = Wb   + (size_t)3 * Cn * Cn;           // 0.79M
  unsigned short* PK   = PQ   + (size_t)Bn * Sn * Cn;
  unsigned short* PKt  = PK   + (size_t)Bn * Sn * Cn;
  unsigned short* Vt   = PKt  + (size_t)Bn * Sn * Cn;
  unsigned short* Abuf = Vt   + (size_t)Bn * Sn * Cn;          // 2.10M
  unsigned short* Mpre = Abuf + (size_t)Bn * NCn * Tn * Tn;    // 33.55M
  float* scale = (float*)(Mpre + (size_t)Bn * NCn * Cn * Cn);  // 16K
  float* zsum  = scale + (size_t)Bn * Sn;                      // 64K
  (void)ws_size; (void)in_sizes; (void)n_in; (void)out_size;

  hipLaunchKernelGGL(k_cast, dim3(4096 + 384), dim3(256), 0, stream, x, Wq, Wk, Wv, xb, Wb);
  hipLaunchKernelGGL(k_proj, dim3(768), dim3(512), 0, stream, xb, Wb, PQ, PK, PKt, Vt, zsum);
  hipLaunchKernelGGL(k_gk, dim3(768), dim3(256), 0, stream,
                     PQ, PK, zsum, Abuf, scale, PKt, Vt, Mpre);
  hipLaunchKernelGGL(k_avinter, dim3(512), dim3(256), 0, stream, Abuf, Vt, PQ, Mpre, scale, out);
}

// Round 14
// 118.428 us; speedup vs baseline: 1.2693x; 1.0550x over previous
//
#include <hip/hip_runtime.h>

// LinearAttentionCell: chunked linear attention, bf16 MFMA.
// R14 = R12 proj geometry (128x128, 256 thr) but BK=64 (8 k-steps, half the
// barrier overhead, 2-buf depth-1 vmcnt(8)) + R13's merged gram/kvp launch.

constexpr int Bn  = 8;
constexpr int Sn  = 2048;
constexpr int Cn  = 512;
constexpr int Tn  = 128;
constexpr int NCn = 16;
constexpr float DKf = 0.04419417382415922f;     // 1/sqrt(512)

typedef __attribute__((ext_vector_type(8))) short bf16x8;
typedef __attribute__((ext_vector_type(4))) float f32x4;

__device__ __forceinline__ unsigned short f2bf(float f) {   // RNE
  unsigned u = __float_as_uint(f);
  u = (u + 0x7fffu + ((u >> 16) & 1u)) >> 16;
  return (unsigned short)u;
}
__device__ __forceinline__ float bf2f(unsigned short h) {
  return __uint_as_float(((unsigned)h) << 16);
}
__device__ __forceinline__ float phi_f(float u) {
  float s = u * DKf;
  return s > 0.0f ? s + 1.0f : __expf(s);       // elu(s)+1
}

// ---------------- merged cast: x -> xb, {Wq,Wk,Wv} -> Wb ---------------------
__global__ __launch_bounds__(256) void k_cast(
    const float* __restrict__ x, const float* __restrict__ Wq,
    const float* __restrict__ Wk, const float* __restrict__ Wv,
    unsigned short* __restrict__ xb, unsigned short* __restrict__ Wb)
{
  const int bid = blockIdx.x;
  const float* src;
  unsigned short* dst;
  size_t i8;
  if (bid < 4096) {
    i8 = ((size_t)bid * 256 + threadIdx.x) * 8;
    src = x; dst = xb;
  } else {
    const size_t f = ((size_t)(bid - 4096) * 256 + threadIdx.x) * 8;
    const int z = (int)(f >> 18);                    // / (512*512)
    src = (z == 0) ? Wq : (z == 1 ? Wk : Wv);
    dst = Wb + ((size_t)z << 18);
    i8 = f & ((1u << 18) - 1);
  }
  float4 a = *(const float4*)&src[i8];
  float4 b = *(const float4*)&src[i8 + 4];
  uint4 o;
  o.x = (unsigned)f2bf(a.x) | ((unsigned)f2bf(a.y) << 16);
  o.y = (unsigned)f2bf(a.z) | ((unsigned)f2bf(a.w) << 16);
  o.z = (unsigned)f2bf(b.x) | ((unsigned)f2bf(b.y) << 16);
  o.w = (unsigned)f2bf(b.z) | ((unsigned)f2bf(b.w) << 16);
  *(uint4*)&dst[i8] = o;
}

// ---- stage a 128x64 bf16 tile global->LDS (256 thr, 4 issues/thread) --------
// 8 slots of 16B per row; swizzle slot ^= row&7 (8-row period, conflict-free).
__device__ __forceinline__ void stage128x64(const unsigned short* __restrict__ g,
                                            int ld, unsigned short* lds,
                                            int wid, int lane) {
#pragma unroll
  for (int e = 0; e < 4; ++e) {
    const int row = e * 32 + wid * 8 + (lane >> 3);
    const int ks  = (lane & 7) ^ (row & 7);
    const unsigned short* src = g + (size_t)row * ld + ks * 8;
    unsigned short* dst = lds + (size_t)(e * 256 + wid * 64) * 8;   // wave-uniform
    __builtin_amdgcn_global_load_lds(
        (const __attribute__((address_space(1))) void*)src,
        (__attribute__((address_space(3))) void*)dst, 16, 0, 0);
  }
}

// ---------------- K1: projections, 128x128 tile, BK=64, 8 k-steps ------------
// 1536 blocks: xcd = bid&7 owns 16 contiguous m-slabs x 4 n x 3 z.
// 2-buffer depth-1 pipeline: stage(kt+1) -> vmcnt(8) -> bar -> 32 MFMA -> bar.
__global__ __launch_bounds__(256) void k_proj(
    const unsigned short* __restrict__ xb, const unsigned short* __restrict__ Wb,
    unsigned short* __restrict__ PQ, unsigned short* __restrict__ PK,
    unsigned short* __restrict__ PKt, unsigned short* __restrict__ Vt,
    float* __restrict__ zsum)
{
  __shared__ unsigned short Al[2 * 8192], Bl[2 * 8192];   // 64 KB
  __shared__ float zbuf[2][128];
  const int bid = blockIdx.x;
  const int xcd = bid & 7, idx = bid >> 3;            // idx in 0..191
  const int n = idx & 3, z = (idx >> 2) % 3, mloc = idx / 12;
  const int n0 = n * 128, m0 = (xcd * 16 + mloc) * 128;
  const int t = threadIdx.x, wid = t >> 6, lane = t & 63;
  const int wm = wid >> 1, wn = wid & 1;
  const int fr = lane & 15, kb = lane >> 4;
  f32x4 acc[4][4];
  const f32x4 zero = {0.f, 0.f, 0.f, 0.f};
#pragma unroll
  for (int m = 0; m < 4; ++m)
#pragma unroll
    for (int nn = 0; nn < 4; ++nn) acc[m][nn] = zero;

  const unsigned short* Ag = xb + (size_t)m0 * Cn;
  const unsigned short* Bg = Wb + (size_t)z * Cn * Cn + (size_t)n0 * Cn;

  stage128x64(Ag, Cn, Al, wid, lane);
  stage128x64(Bg, Cn, Bl, wid, lane);
  int cur = 0;
  for (int kt = 0; kt < 8; ++kt) {            // BK=64: 8 k-steps over K=512
    const int nxt = cur ^ 1;
    if (kt + 1 < 8) {
      stage128x64(Ag + (kt + 1) * 64, Cn, Al + nxt * 8192, wid, lane);
      stage128x64(Bg + (kt + 1) * 64, Cn, Bl + nxt * 8192, wid, lane);
      asm volatile("s_waitcnt vmcnt(8)" ::: "memory");   // tile kt landed
    } else {
      asm volatile("s_waitcnt vmcnt(0)" ::: "memory");
    }
    __builtin_amdgcn_s_barrier();
    asm volatile("" ::: "memory");
    const unsigned short* Ac = Al + cur * 8192;
    const unsigned short* Bc = Bl + cur * 8192;
#pragma unroll
    for (int kk = 0; kk < 2; ++kk) {          // two K=32 sub-tiles
      bf16x8 af[4], bf[4];
#pragma unroll
      for (int m = 0; m < 4; ++m) {
        const int r = wm * 64 + m * 16 + fr;
        af[m] = *(const bf16x8*)&Ac[r * 64 + (((kk * 4 + kb) ^ (r & 7)) << 3)];
      }
#pragma unroll
      for (int nn = 0; nn < 4; ++nn) {
        const int r = wn * 64 + nn * 16 + fr;
        bf[nn] = *(const bf16x8*)&Bc[r * 64 + (((kk * 4 + kb) ^ (r & 7)) << 3)];
      }
      __builtin_amdgcn_s_setprio(1);
#pragma unroll
      for (int m = 0; m < 4; ++m)
#pragma unroll
        for (int nn = 0; nn < 4; ++nn)
          acc[m][nn] = __builtin_amdgcn_mfma_f32_16x16x32_bf16(af[m], bf[nn], acc[m][nn], 0, 0, 0);
      __builtin_amdgcn_s_setprio(0);
    }
    __builtin_amdgcn_s_barrier();             // all waves done reading cur
    asm volatile("" ::: "memory");
    cur = nxt;
  }

  float ps[4] = {0.f, 0.f, 0.f, 0.f};
#pragma unroll
  for (int m = 0; m < 4; ++m)
#pragma unroll
    for (int nn = 0; nn < 4; ++nn) {
      const int row0 = m0 + wm * 64 + m * 16 + ((lane >> 4) << 2);
      const int col  = n0 + wn * 64 + nn * 16 + fr;
      f32x4 v = acc[m][nn];
      if (z == 0) {
#pragma unroll
        for (int j = 0; j < 4; ++j)
          PQ[(size_t)(row0 + j) * Cn + col] = f2bf(phi_f(v[j]));
      } else if (z == 1) {
        ushort4 p;
#pragma unroll
        for (int j = 0; j < 4; ++j) {
          unsigned short u = f2bf(phi_f(v[j]));
          PK[(size_t)(row0 + j) * Cn + col] = u;
          (&p.x)[j] = u;
          ps[nn] += bf2f(u);
        }
        const int b = row0 >> 11, tq = row0 & (Sn - 1);
        *(ushort4*)&PKt[((size_t)b * Cn + col) * Sn + tq] = p;
      } else {
        ushort4 p;
#pragma unroll
        for (int j = 0; j < 4; ++j) (&p.x)[j] = f2bf(v[j]);
        const int b = row0 >> 11, tq = row0 & (Sn - 1);
        *(ushort4*)&Vt[((size_t)b * Cn + col) * Sn + tq] = p;
      }
    }

  if (z == 1) {   // block covers one (b, chunk) x cols n0..n0+127 completely
#pragma unroll
    for (int nn = 0; nn < 4; ++nn) {
      float v = ps[nn];
      v += __shfl_xor(v, 16); v += __shfl_xor(v, 32);   // reduce over kb
      if (lane < 16) zbuf[wm][wn * 64 + nn * 16 + lane] = v;
    }
    __syncthreads();
    if (t < 128) {
      const int b = m0 >> 11, ch = (m0 >> 7) & 15;
      zsum[((size_t)b * NCn + ch) * Cn + n0 + t] = zbuf[0][t] + zbuf[1][t];
    }
  }
}

// ---- gram staging: A 64x32 (1 load/thread), B 128x32 (2 loads/thread) -------
__device__ __forceinline__ void stageA64(const unsigned short* __restrict__ g,
                                         unsigned short* lds, int wid, int lane) {
  const int row = wid * 16 + (lane >> 2);
  const int ks  = (lane & 3) ^ ((row >> 1) & 3);
  __builtin_amdgcn_global_load_lds(
      (const __attribute__((address_space(1))) void*)(g + (size_t)row * Cn + ks * 8),
      (__attribute__((address_space(3))) void*)(lds + wid * 512), 16, 0, 0);
}
__device__ __forceinline__ void stageB128(const unsigned short* __restrict__ g,
                                          unsigned short* lds, int wid, int lane) {
#pragma unroll
  for (int e = 0; e < 2; ++e) {
    const int row = e * 64 + wid * 16 + (lane >> 2);
    const int ks  = (lane & 3) ^ ((row >> 1) & 3);
    __builtin_amdgcn_global_load_lds(
        (const __attribute__((address_space(1))) void*)(g + (size_t)row * Cn + ks * 8),
        (__attribute__((address_space(3))) void*)(lds + e * 2048 + wid * 512),
        16, 0, 0);
  }
}

// ---- stage a 64x128 bf16 tile global->LDS, swizzle slot ^= row&7 ------------
__device__ __forceinline__ void stage64x128(const unsigned short* __restrict__ g,
                                            int ld, unsigned short* lds,
                                            int wid, int lane) {
#pragma unroll
  for (int i = 0; i < 4; ++i) {
    const int row = wid * 16 + i * 4 + (lane >> 4);
    const int s   = (lane & 15) ^ (row & 7);
    const unsigned short* src = g + (size_t)row * ld + s * 8;
    unsigned short* dst = lds + (size_t)(wid * 16 + i * 4) * 128;   // wave-uniform
    __builtin_amdgcn_global_load_lds(
        (const __attribute__((address_space(1))) void*)src,
        (__attribute__((address_space(3))) void*)dst, 16, 0, 0);
  }
}

// ---------------- K2: merged gram (blocks 512..767) + kvp (blocks 0..511) ----
__global__ __launch_bounds__(256) void k_gk(
    const unsigned short* __restrict__ PQ, const unsigned short* __restrict__ PK,
    const float* __restrict__ zsum,
    unsigned short* __restrict__ Abuf, float* __restrict__ scale,
    const unsigned short* __restrict__ PKt, const unsigned short* __restrict__ Vt,
    unsigned short* __restrict__ Mpre)
{
  __shared__ unsigned short smem[32768];   // 64 KB union
  const int t = threadIdx.x, wid = t >> 6, lane = t & 63;
  const int fr = lane & 15, kb = lane >> 4;
  const f32x4 zero = {0.f, 0.f, 0.f, 0.f};

  if (blockIdx.x < 512) {
    // ---------------- kvp: KV + exclusive prefix (BK=128) -------------------
    unsigned short* Al = smem;                  // 2 x 8192
    unsigned short* Bl = smem + 16384;          // 2 x 8192
    const int bid = blockIdx.x;
    const int b = bid & 7, idx = bid >> 3;
    const int d0 = (idx & 7) * 64, c0 = (idx >> 3) * 64;
    const int wm = wid >> 1, wn = wid & 1;
    f32x4 acc[2][2];
#pragma unroll
    for (int m = 0; m < 2; ++m)
#pragma unroll
      for (int n = 0; n < 2; ++n) acc[m][n] = zero;
    const unsigned short* Ag = PKt + ((size_t)b * Cn + c0) * Sn;
    const unsigned short* Bg = Vt  + ((size_t)b * Cn + d0) * Sn;
    stage64x128(Ag, Sn, Al, wid, lane);
    stage64x128(Bg, Sn, Bl, wid, lane);
    int cur = 0;
    for (int ch = 0; ch < NCn; ++ch) {
      const int nxt = cur ^ 1;
      if (ch + 1 < NCn) {
        stage64x128(Ag + (ch + 1) * Tn, Sn, Al + nxt * 8192, wid, lane);
        stage64x128(Bg + (ch + 1) * Tn, Sn, Bl + nxt * 8192, wid, lane);
        asm volatile("s_waitcnt vmcnt(8)" ::: "memory");
      } else {
        asm volatile("s_waitcnt vmcnt(0)" ::: "memory");
      }
      __builtin_amdgcn_s_barrier();
      asm volatile("" ::: "memory");
      if (ch > 0) {
#pragma unroll
        for (int m = 0; m < 2; ++m)
#pragma unroll
          for (int n = 0; n < 2; ++n) {
            const int c_row = c0 + wm * 32 + m * 16 + (kb << 2);
            const int d     = d0 + wn * 32 + n * 16 + fr;
            ushort4 p;
#pragma unroll
            for (int j = 0; j < 4; ++j) (&p.x)[j] = f2bf(acc[m][n][j]);
            *(ushort4*)&Mpre[((size_t)(b * NCn + ch) * Cn + d) * Cn + c_row] = p;
          }
      }
      const unsigned short* Ac = Al + cur * 8192;
      const unsigned short* Bc = Bl + cur * 8192;
      __builtin_amdgcn_s_setprio(1);
#pragma unroll
      for (int kt = 0; kt < 4; ++kt) {
        bf16x8 af[2], bf[2];
#pragma unroll
        for (int m = 0; m < 2; ++m) {
          const int r = wm * 32 + m * 16 + fr;
          af[m] = *(const bf16x8*)&Ac[r * 128 + (((kt * 4 + kb) ^ (r & 7)) << 3)];
        }
#pragma unroll
        for (int n = 0; n < 2; ++n) {
          const int r = wn * 32 + n * 16 + fr;
          bf[n] = *(const bf16x8*)&Bc[r * 128 + (((kt * 4 + kb) ^ (r & 7)) << 3)];
        }
#pragma unroll
        for (int m = 0; m < 2; ++m)
#pragma unroll
          for (int n = 0; n < 2; ++n)
            acc[m][n] = __builtin_amdgcn_mfma_f32_16x16x32_bf16(af[m], bf[n], acc[m][n], 0, 0, 0);
      }
      __builtin_amdgcn_s_setprio(0);
      __builtin_amdgcn_s_barrier();
      asm volatile("" ::: "memory");
      cur = nxt;
    }
  } else {
    // ---------------- gram: A = tril(PQ_c PK_c^T), scale fused --------------
    unsigned short* Asl = smem;                 // 3 x 2048
    unsigned short* Bsl = smem + 6144;          // 3 x 4096
    float* rsmem = (float*)(smem + 18432);      // [4][64]
    float* zpl   = rsmem + 256;                 // [512]
    const int g = blockIdx.x - 512;
    const int i0 = (g & 1) * 64, ch = (g >> 1) & 15, b = g >> 5;
    const unsigned short* Aq = PQ + ((size_t)(b * Sn + ch * Tn + i0)) * Cn;
    const unsigned short* Bk = PK + ((size_t)(b * Sn + ch * Tn)) * Cn;
    f32x4 acc[4][2];
#pragma unroll
    for (int m = 0; m < 4; ++m)
#pragma unroll
      for (int n = 0; n < 2; ++n) acc[m][n] = zero;

    stageA64(Aq, Asl, wid, lane);
    stageB128(Bk, Bsl, wid, lane);
    stageA64(Aq + 32, Asl + 2048, wid, lane);
    stageB128(Bk + 32, Bsl + 4096, wid, lane);
    int cur = 0;
    for (int kt = 0; kt < 16; ++kt) {
      if (kt + 2 < 16) {
        const int nx2 = (cur + 2 >= 3) ? cur - 1 : cur + 2;
        stageA64(Aq + (kt + 2) * 32, Asl + nx2 * 2048, wid, lane);
        stageB128(Bk + (kt + 2) * 32, Bsl + nx2 * 4096, wid, lane);
        asm volatile("s_waitcnt vmcnt(6)" ::: "memory");
      } else if (kt + 1 < 16) {
        asm volatile("s_waitcnt vmcnt(3)" ::: "memory");
      } else {
        asm volatile("s_waitcnt vmcnt(0)" ::: "memory");
      }
      __builtin_amdgcn_s_barrier();
      asm volatile("" ::: "memory");
      const unsigned short* Ac = Asl + cur * 2048;
      const unsigned short* Bc = Bsl + cur * 4096;
      bf16x8 af[4], bf[2];
#pragma unroll
      for (int m = 0; m < 4; ++m) {
        const int r = m * 16 + fr;
        af[m] = *(const bf16x8*)&Ac[r * 32 + ((kb ^ ((r >> 1) & 3)) << 3)];
      }
#pragma unroll
      for (int n = 0; n < 2; ++n) {
        const int c = wid * 32 + n * 16 + fr;
        bf[n] = *(const bf16x8*)&Bc[c * 32 + ((kb ^ ((c >> 1) & 3)) << 3)];
      }
      __builtin_amdgcn_s_setprio(1);
#pragma unroll
      for (int m = 0; m < 4; ++m)
#pragma unroll
        for (int n = 0; n < 2; ++n)
          acc[m][n] = __builtin_amdgcn_mfma_f32_16x16x32_bf16(af[m], bf[n], acc[m][n], 0, 0, 0);
      __builtin_amdgcn_s_setprio(0);
      __builtin_amdgcn_s_barrier();
      asm volatile("" ::: "memory");
      cur = (cur + 1 >= 3) ? 0 : cur + 1;
    }

    float rsum[4][4];
#pragma unroll
    for (int m = 0; m < 4; ++m)
#pragma unroll
      for (int j = 0; j < 4; ++j) rsum[m][j] = 0.f;
#pragma unroll
    for (int m = 0; m < 4; ++m)
#pragma unroll
      for (int n = 0; n < 2; ++n) {
        f32x4 v = acc[m][n];
#pragma unroll
        for (int j = 0; j < 4; ++j) {
          const int row_g = i0 + m * 16 + kb * 4 + j;     // chunk-local row
          const int col   = wid * 32 + n * 16 + fr;
          unsigned short u = (col <= row_g) ? f2bf(v[j]) : 0;
          Abuf[((size_t)(b * NCn + ch) * Tn + row_g) * Tn + col] = u;
          rsum[m][j] += bf2f(u);
        }
      }
#pragma unroll
    for (int m = 0; m < 4; ++m)
#pragma unroll
      for (int j = 0; j < 4; ++j) {
        float r = rsum[m][j];
        r += __shfl_xor(r, 1); r += __shfl_xor(r, 2);
        r += __shfl_xor(r, 4); r += __shfl_xor(r, 8);
        if (fr == 0) rsmem[wid * 64 + m * 16 + kb * 4 + j] = r;
      }
    // exclusive chunk-prefix of zsum -> zpl
#pragma unroll
    for (int e = 0; e < 2; ++e) {
      const int c = t + e * 256;
      float s = 0.f;
      for (int ch2 = 0; ch2 < ch; ++ch2)
        s += zsum[((size_t)b * NCn + ch2) * Cn + c];
      zpl[c] = s;
    }
    __syncthreads();
    // per-row dot(PQ_row, zpl): 4 threads per row, 128 cols each
    const int row = t >> 2, q4 = (t & 3) * 128;
    const unsigned short* pq = Aq + (size_t)row * Cn + q4;
    float dacc = 0.f;
    for (int i = 0; i < 128; i += 8) {
      uint4 q = *(const uint4*)(pq + i);
      dacc += bf2f((unsigned short)(q.x & 0xffff)) * zpl[q4 + i + 0]
            + bf2f((unsigned short)(q.x >> 16))    * zpl[q4 + i + 1]
            + bf2f((unsigned short)(q.y & 0xffff)) * zpl[q4 + i + 2]
            + bf2f((unsigned short)(q.y >> 16))    * zpl[q4 + i + 3]
            + bf2f((unsigned short)(q.z & 0xffff)) * zpl[q4 + i + 4]
            + bf2f((unsigned short)(q.z >> 16))    * zpl[q4 + i + 5]
            + bf2f((unsigned short)(q.w & 0xffff)) * zpl[q4 + i + 6]
            + bf2f((unsigned short)(q.w >> 16))    * zpl[q4 + i + 7];
    }
    dacc += __shfl_xor(dacc, 1);
    dacc += __shfl_xor(dacc, 2);
    if ((t & 3) == 0)
      scale[(size_t)b * Sn + ch * Tn + i0 + row] =
          rsmem[0 * 64 + row] + rsmem[1 * 64 + row] +
          rsmem[2 * 64 + row] + rsmem[3 * 64 + row] + dacc + 1e-5f;
  }
}

// ---- stage a 128x32 bf16 tile global->LDS (256 thr), kslot ^= (row>>1)&3 ----
__device__ __forceinline__ void stage128x32(const unsigned short* __restrict__ g,
                                            int ld, unsigned short* lds,
                                            int wid, int lane) {
#pragma unroll
  for (int cc = 0; cc < 2; ++cc) {
    const int row = cc * 64 + wid * 16 + (lane >> 2);
    const int ks  = (lane & 3) ^ ((row >> 1) & 3);
    const unsigned short* src = g + (size_t)row * ld + ks * 8;
    unsigned short* dst = lds + (size_t)(cc * 256 + wid * 64) * 8;  // wave-uniform
    __builtin_amdgcn_global_load_lds(
        (const __attribute__((address_space(1))) void*)src,
        (__attribute__((address_space(3))) void*)dst, 16, 0, 0);
  }
}

// ---------------- K3: out = (A@V_c + PQ_c@Mpre_c) / scale --------------------
// Single fused 20-step pipelined K-loop (intra kt<4, inter kt>=4).
__global__ __launch_bounds__(256) void k_avinter(
    const unsigned short* __restrict__ Abuf, const unsigned short* __restrict__ Vt,
    const unsigned short* __restrict__ PQ, const unsigned short* __restrict__ Mpre,
    const float* __restrict__ scale, float* __restrict__ out)
{
  __shared__ unsigned short Al[3 * 128 * 32], Bl[3 * 128 * 32];
  const int bid = blockIdx.x;
  const int logical = (bid & 7) * 64 + (bid >> 3);
  const int d0 = (logical & 3) * 128;
  const int ch = (logical >> 2) & 15;
  const int b  = logical >> 6;
  const int t0 = ch * Tn;
  const int t = threadIdx.x, wid = t >> 6, lane = t & 63;
  const int wm = wid >> 1, wn = wid & 1;
  const int fr = lane & 15, kb = lane >> 4;
  f32x4 acc[4][4];
  const f32x4 zero = {0.f, 0.f, 0.f, 0.f};
#pragma unroll
  for (int m = 0; m < 4; ++m)
#pragma unroll
    for (int n = 0; n < 4; ++n) acc[m][n] = zero;

  const unsigned short* Aintra = Abuf + (size_t)(b * NCn + ch) * Tn * Tn;
  const unsigned short* Bintra = Vt + ((size_t)b * Cn + d0) * Sn + t0;
  const unsigned short* Ainter = PQ + ((size_t)b * Sn + t0) * Cn;
  const unsigned short* Binter = Mpre + ((size_t)(b * NCn + ch) * Cn + d0) * Cn;
  auto srcA = [&](int kt) { return (kt < 4) ? Aintra + kt * 32 : Ainter + (kt - 4) * 32; };
  auto srcB = [&](int kt) { return (kt < 4) ? Bintra + kt * 32 : Binter + (kt - 4) * 32; };
  auto ldA  = [&](int kt) { return (kt < 4) ? Tn : Cn; };
  auto ldB  = [&](int kt) { return (kt < 4) ? Sn : Cn; };
  const int nkt = (ch > 0) ? 20 : 4;

  stage128x32(srcA(0), ldA(0), Al, wid, lane);
  stage128x32(srcB(0), ldB(0), Bl, wid, lane);
  stage128x32(srcA(1), ldA(1), Al + 4096, wid, lane);
  stage128x32(srcB(1), ldB(1), Bl + 4096, wid, lane);
  int cur = 0;
  for (int kt = 0; kt < nkt; ++kt) {
    if (kt + 2 < nkt) {
      const int nx2 = (cur + 2 >= 3) ? cur - 1 : cur + 2;
      stage128x32(srcA(kt + 2), ldA(kt + 2), Al + nx2 * 4096, wid, lane);
      stage128x32(srcB(kt + 2), ldB(kt + 2), Bl + nx2 * 4096, wid, lane);
      asm volatile("s_waitcnt vmcnt(8)" ::: "memory");
    } else if (kt + 1 < nkt) {
      asm volatile("s_waitcnt vmcnt(4)" ::: "memory");
    } else {
      asm volatile("s_waitcnt vmcnt(0)" ::: "memory");
    }
    __builtin_amdgcn_s_barrier();
    asm volatile("" ::: "memory");
    const unsigned short* Ac = Al + cur * 4096;
    const unsigned short* Bc = Bl + cur * 4096;
    bf16x8 af[4], bf[4];
#pragma unroll
    for (int m = 0; m < 4; ++m) {
      const int r = wm * 64 + m * 16 + fr;
      af[m] = *(const bf16x8*)&Ac[r * 32 + ((kb ^ ((r >> 1) & 3)) << 3)];
    }
#pragma unroll
    for (int n = 0; n < 4; ++n) {
      const int r = wn * 64 + n * 16 + fr;
      bf[n] = *(const bf16x8*)&Bc[r * 32 + ((kb ^ ((r >> 1) & 3)) << 3)];
    }
    __builtin_amdgcn_s_setprio(1);
#pragma unroll
    for (int m = 0; m < 4; ++m)
#pragma unroll
      for (int n = 0; n < 4; ++n)
        acc[m][n] = __builtin_amdgcn_mfma_f32_16x16x32_bf16(af[m], bf[n], acc[m][n], 0, 0, 0);
    __builtin_amdgcn_s_setprio(0);
    __builtin_amdgcn_s_barrier();
    asm volatile("" ::: "memory");
    cur = (cur + 1 >= 3) ? 0 : cur + 1;
  }

#pragma unroll
  for (int m = 0; m < 4; ++m)
#pragma unroll
    for (int n = 0; n < 4; ++n) {
      const int row0 = t0 + wm * 64 + m * 16 + ((lane >> 4) << 2);
      const int col  = d0 + wn * 64 + n * 16 + (lane & 15);
      f32x4 v = acc[m][n];
#pragma unroll
      for (int j = 0; j < 4; ++j) {
        const size_t sidx = (size_t)b * Sn + row0 + j;
        out[sidx * Cn + col] = v[j] / scale[sidx];
      }
    }
}

// ---------------- launch -----------------------------------------------------
extern "C" void kernel_launch(void* const* d_in, const int* in_sizes, int n_in,
                              void* d_out, int out_size, void* d_ws, size_t ws_size,
                              hipStream_t stream)
{
  const float* x  = (const float*)d_in[0];
  const float* Wq = (const float*)d_in[1];
  const float* Wk = (const float*)d_in[2];
  const float* Wv = (const float*)d_in[3];
  float* out = (float*)d_out;

  unsigned short* xb   = (unsigned short*)d_ws;
  unsigned short* Wb   = xb   + (size_t)Bn * Sn * Cn;          // 8.39M
  unsigned short* PQ   = Wb   + (size_t)3 * Cn * Cn;           // 0.79M
  unsigned short* PK   = PQ   + (size_t)Bn * Sn * Cn;
  unsigned short* PKt  = PK   + (size_t)Bn * Sn * Cn;
  unsigned short* Vt   = PKt  + (size_t)Bn * Sn * Cn;
  unsigned short* Abuf = Vt   + (size_t)Bn * Sn * Cn;          // 2.10M
  unsigned short* Mpre = Abuf + (size_t)Bn * NCn * Tn * Tn;    // 33.55M
  float* scale = (float*)(Mpre + (size_t)Bn * NCn * Cn * Cn);  // 16K
  float* zsum  = scale + (size_t)Bn * Sn;                      // 64K
  (void)ws_size; (void)in_sizes; (void)n_in; (void)out_size;

  hipLaunchKernelGGL(k_cast, dim3(4096 + 384), dim3(256), 0, stream, x, Wq, Wk, Wv, xb, Wb);
  hipLaunchKernelGGL(k_proj, dim3(1536), dim3(256), 0, stream, xb, Wb, PQ, PK, PKt, Vt, zsum);
  hipLaunchKernelGGL(k_gk, dim3(768), dim3(256), 0, stream,
                     PQ, PK, zsum, Abuf, scale, PKt, Vt, Mpre);
  hipLaunchKernelGGL(k_avinter, dim3(512), dim3(256), 0, stream, Abuf, Vt, PQ, Mpre, scale, out);
}